// Round 4
// baseline (318.341 us; speedup 1.0000x reference)
//
#include <hip/hip_runtime.h>
#include <hip/hip_bf16.h>
#include <math.h>

#define N_NODES 50000
#define N_EDGES 400000
#define HEADS   4
#define HC      512
#define IN_DIM  5
#define M_SEL   25000
#define NEG_SLOPE 0.2f

typedef __attribute__((ext_vector_type(8))) short bf16x8;
typedef __attribute__((ext_vector_type(4))) float f32x4;

__device__ inline unsigned short f2bf(float f) {
    union { float f; unsigned u; } v; v.f = f;
    unsigned r = v.u + 0x7FFF + ((v.u >> 16) & 1);   // RNE
    return (unsigned short)(r >> 16);
}
__device__ inline float bf2f(unsigned short b) {
    union { unsigned u; float f; } v; v.u = ((unsigned)b) << 16;
    return v.f;
}

// ---------------------------------------------------------------------------
// fp32 -> bf16 conversion for W1 and W2 in one launch (2 x 65536 float4)
// ---------------------------------------------------------------------------
__global__ void k_cvt2(const float* __restrict__ W1, const float* __restrict__ W2,
                       unsigned short* __restrict__ W1b, unsigned short* __restrict__ W2b) {
    int i = blockIdx.x * 256 + threadIdx.x;
    const float* src = (i < 65536) ? W1 : W2;
    unsigned short* dst = (i < 65536) ? W1b : W2b;
    int j = i & 65535;
    float4 v = ((const float4*)src)[j];
    ushort4 o;
    o.x = f2bf(v.x); o.y = f2bf(v.y); o.z = f2bf(v.z); o.w = f2bf(v.w);
    ((ushort4*)dst)[j] = o;
}

// ---------------------------------------------------------------------------
// Kernel 1: h = x @ W.T (bf16); a_src/a_dst einsum [N,4] f32; deg init to 1.
// Register-resident weights (160B contiguous per lane), 8 nodes per wave.
// ---------------------------------------------------------------------------
#define TR_NPW 8

__global__ __launch_bounds__(256) void k_transform(
        const float* __restrict__ x, const float* __restrict__ W,
        const float* __restrict__ att_src, const float* __restrict__ att_dst,
        unsigned short* __restrict__ h, float* __restrict__ a_src,
        float* __restrict__ a_dst, int* __restrict__ deg) {
    int wave = threadIdx.x >> 6, lane = threadIdx.x & 63;
    int c0 = lane * 8;

    float wreg[40];
    const float4* wp = (const float4*)(W + c0 * IN_DIM);
#pragma unroll
    for (int i = 0; i < 10; i++) ((float4*)wreg)[i] = wp[i];
    float sas[8], sad[8];
    *(float4*)&sas[0] = *(const float4*)(att_src + c0);
    *(float4*)&sas[4] = *(const float4*)(att_src + c0 + 4);
    *(float4*)&sad[0] = *(const float4*)(att_dst + c0);
    *(float4*)&sad[4] = *(const float4*)(att_dst + c0 + 4);

    int n0 = (blockIdx.x * 4 + wave) * TR_NPW;
#pragma unroll
    for (int t = 0; t < TR_NPW; t++) {
        int n = n0 + t;
        if (n >= N_NODES) return;
        float xv[IN_DIM];
#pragma unroll
        for (int i = 0; i < IN_DIM; i++) xv[i] = x[n * IN_DIM + i];

        float ps = 0.f, pd = 0.f;
        bf16x8 hv8;
#pragma unroll
        for (int j = 0; j < 8; j++) {
            float acc = 0.f;
#pragma unroll
            for (int i = 0; i < IN_DIM; i++) acc += xv[i] * wreg[j * IN_DIM + i];
            hv8[j] = (short)f2bf(acc);
            ps += acc * sas[j];
            pd += acc * sad[j];
        }
        *(bf16x8*)(h + (size_t)n * HC + c0) = hv8;

#pragma unroll
        for (int off = 8; off >= 1; off >>= 1) {
            ps += __shfl_xor(ps, off);
            pd += __shfl_xor(pd, off);
        }
        if ((lane & 15) == 0) {
            int head = lane >> 4;
            a_src[n * HEADS + head] = ps;
            a_dst[n * HEADS + head] = pd;
        }
        if (lane == 0) deg[n] = 1;   // self-loop base for histogram
    }
}

// ---------------------------------------------------------------------------
// CSR build
// ---------------------------------------------------------------------------
__global__ void k_hist(const int* __restrict__ ei, int* __restrict__ deg) {
    int e = blockIdx.x * 256 + threadIdx.x;
    if (e < N_EDGES) atomicAdd(&deg[ei[N_EDGES + e]], 1);
}

// single-block scan over 50000 degrees + self-loop fill + cursor init
__global__ __launch_bounds__(1024) void k_scanfill(const int* __restrict__ deg,
                                                   int* __restrict__ offs,
                                                   int* __restrict__ curs,
                                                   int* __restrict__ csr) {
    __shared__ int part[1024];
    int tid = threadIdx.x;
    int start = tid * 49;
    int end = start + 49; if (end > N_NODES) end = N_NODES;
    int sum = 0;
    for (int i = start; i < end; i++) sum += deg[i];
    part[tid] = sum;
    __syncthreads();
    for (int off = 1; off < 1024; off <<= 1) {
        int t = (tid >= off) ? part[tid - off] : 0;
        __syncthreads();
        part[tid] += t;
        __syncthreads();
    }
    int base = part[tid] - sum;   // exclusive prefix
    for (int i = start; i < end; i++) {
        offs[i] = base;
        csr[base] = i;            // self loop in slot 0
        curs[i] = base + 1;
        base += deg[i];
    }
}

__global__ void k_fill_edges(const int* __restrict__ ei, int* __restrict__ cursor,
                             int* __restrict__ csr) {
    int e = blockIdx.x * 256 + threadIdx.x;
    if (e < N_EDGES) {
        int d = ei[N_EDGES + e];
        int pos = atomicAdd(&cursor[d], 1);
        csr[pos] = ei[e];
    }
}

// ---------------------------------------------------------------------------
// Aggregate — TEAM NODES ONLY, one wave per dst node.
// Fast path (dn<=16, ~99.2%): single pass; lane (lane&15) owns one edge's
// logit for head (lane>>4); shuffle-reduced softmax; 4x-unrolled gather.
// ---------------------------------------------------------------------------
__global__ void k_aggregate(const unsigned short* __restrict__ h, const float* __restrict__ a_src,
                            const float* __restrict__ a_dst, const int* __restrict__ csr,
                            const int* __restrict__ offs, const int* __restrict__ deg,
                            const float* __restrict__ bias, unsigned short* __restrict__ emb_sel) {
    int wave = threadIdx.x >> 6, lane = threadIdx.x & 63;
    int w = blockIdx.x * 4 + wave;
    if (w >= M_SEL) return;
    int n = ((w >> 2) << 3) + (w & 3);   // TEAM_IDX[w]

    int base = offs[n];
    int dn = deg[n];
    int head = lane >> 4, egrp = lane & 15;
    float adn = a_dst[n * HEADS + head];
    int c0 = lane * 8;

    float acc[8];
#pragma unroll
    for (int j = 0; j < 8; j++) acc[j] = -INFINITY;

    if (dn <= 16) {
        int s_e = 0;
        float t = -INFINITY;
        if (egrp < dn) {
            s_e = csr[base + egrp];
            t = a_src[s_e * HEADS + head] + adn;
            t = (t > 0.f) ? t : NEG_SLOPE * t;
        }
        float m = t;
#pragma unroll
        for (int off = 8; off >= 1; off >>= 1) m = fmaxf(m, __shfl_xor(m, off));
        float ex = (egrp < dn) ? __expf(t - m) : 0.f;
        float den = ex;
#pragma unroll
        for (int off = 8; off >= 1; off >>= 1) den += __shfl_xor(den, off);
        float attn = ex / den;   // this lane's edge attn (for its head)

        int e = 0;
        for (; e + 4 <= dn; e += 4) {
            int s0 = __shfl(s_e, e + 0), s1 = __shfl(s_e, e + 1);
            int s2 = __shfl(s_e, e + 2), s3 = __shfl(s_e, e + 3);
            float a0 = __shfl(attn, (head << 4) | (e + 0));
            float a1 = __shfl(attn, (head << 4) | (e + 1));
            float a2 = __shfl(attn, (head << 4) | (e + 2));
            float a3 = __shfl(attn, (head << 4) | (e + 3));
            bf16x8 v0 = *(const bf16x8*)(h + (size_t)s0 * HC + c0);
            bf16x8 v1 = *(const bf16x8*)(h + (size_t)s1 * HC + c0);
            bf16x8 v2 = *(const bf16x8*)(h + (size_t)s2 * HC + c0);
            bf16x8 v3 = *(const bf16x8*)(h + (size_t)s3 * HC + c0);
#pragma unroll
            for (int j = 0; j < 8; j++) {
                acc[j] = fmaxf(acc[j], bf2f((unsigned short)v0[j]) * a0);
                acc[j] = fmaxf(acc[j], bf2f((unsigned short)v1[j]) * a1);
                acc[j] = fmaxf(acc[j], bf2f((unsigned short)v2[j]) * a2);
                acc[j] = fmaxf(acc[j], bf2f((unsigned short)v3[j]) * a3);
            }
        }
        for (; e < dn; e++) {
            int s = __shfl(s_e, e);
            float a = __shfl(attn, (head << 4) | e);
            bf16x8 v = *(const bf16x8*)(h + (size_t)s * HC + c0);
#pragma unroll
            for (int j = 0; j < 8; j++)
                acc[j] = fmaxf(acc[j], bf2f((unsigned short)v[j]) * a);
        }
    } else {
        // fallback: 3-pass (rare, dn>16)
        float m = -INFINITY;
        for (int e0 = 0; e0 < dn; e0 += 16) {
            int e = e0 + egrp;
            if (e < dn) {
                int s = csr[base + e];
                float t = a_src[s * HEADS + head] + adn;
                t = (t > 0.f) ? t : NEG_SLOPE * t;
                m = fmaxf(m, t);
            }
        }
#pragma unroll
        for (int off = 8; off >= 1; off >>= 1) m = fmaxf(m, __shfl_xor(m, off));
        float den = 0.f;
        for (int e0 = 0; e0 < dn; e0 += 16) {
            int e = e0 + egrp;
            if (e < dn) {
                int s = csr[base + e];
                float t = a_src[s * HEADS + head] + adn;
                t = (t > 0.f) ? t : NEG_SLOPE * t;
                den += __expf(t - m);
            }
        }
#pragma unroll
        for (int off = 8; off >= 1; off >>= 1) den += __shfl_xor(den, off);
        float invden = 1.0f / den;
        for (int e = 0; e < dn; e++) {
            int s = csr[base + e];
            float t = a_src[s * HEADS + head] + adn;
            t = (t > 0.f) ? t : NEG_SLOPE * t;
            float attn = __expf(t - m) * invden;
            bf16x8 hv = *(const bf16x8*)(h + (size_t)s * HC + c0);
#pragma unroll
            for (int j = 0; j < 8; j++)
                acc[j] = fmaxf(acc[j], bf2f((unsigned short)hv[j]) * attn);
        }
    }

    bf16x8 ov;
#pragma unroll
    for (int j = 0; j < 8; j++) ov[j] = (short)f2bf(acc[j] + bias[c0 + j]);
    *(bf16x8*)(emb_sel + (size_t)w * HC + c0) = ov;
}

// ---------------------------------------------------------------------------
// bf16 MFMA GEMM:  C[m,o] = relu( sum_k A[m,k]*Wt[o,k] + bias[o] ) -> bf16
// 256x256 tile, BK=64, 512 threads (4m x 2n waves, 64x128/wave).
// LDS rows padded to 72 shorts. Register-staged prefetch.
// ---------------------------------------------------------------------------
#define BK  64
#define LDK 72

template <bool RELU>
__global__ __launch_bounds__(512, 2) void k_gemm(const unsigned short* __restrict__ A, int M,
                                                 const unsigned short* __restrict__ Wt,
                                                 const float* __restrict__ bias,
                                                 unsigned short* __restrict__ C) {
    __shared__ unsigned short As[256 * LDK];
    __shared__ unsigned short Bs[256 * LDK];
    int tid = threadIdx.x;
    int m0 = blockIdx.y * 256;
    int o0 = blockIdx.x * 256;
    int wv = tid >> 6, lane = tid & 63;
    int wm = wv >> 1, wn = wv & 1;   // 4 x 2 wave grid

    f32x4 acc[4][8];
#pragma unroll
    for (int i = 0; i < 4; i++)
#pragma unroll
        for (int j = 0; j < 8; j++) acc[i][j] = (f32x4){0.f, 0.f, 0.f, 0.f};

    bf16x8 ra[4], rb[4];
#pragma unroll
    for (int s = 0; s < 4; s++) {
        int c = s * 512 + tid;           // 0..2047
        int row = c >> 3, col = (c & 7) * 8;
        int m = m0 + row;
        bf16x8 av = {0, 0, 0, 0, 0, 0, 0, 0};
        if (m < M) av = *(const bf16x8*)(A + (size_t)m * HC + col);
        ra[s] = av;
        rb[s] = *(const bf16x8*)(Wt + (size_t)(o0 + row) * HC + col);
    }

    for (int k0 = 0; k0 < HC; k0 += BK) {
        __syncthreads();
#pragma unroll
        for (int s = 0; s < 4; s++) {
            int c = s * 512 + tid;
            int row = c >> 3, col = (c & 7) * 8;
            *(bf16x8*)(&As[row * LDK + col]) = ra[s];
            *(bf16x8*)(&Bs[row * LDK + col]) = rb[s];
        }
        __syncthreads();

        int kn = k0 + BK;
        if (kn < HC) {
#pragma unroll
            for (int s = 0; s < 4; s++) {
                int c = s * 512 + tid;
                int row = c >> 3, col = (c & 7) * 8;
                int m = m0 + row;
                bf16x8 av = {0, 0, 0, 0, 0, 0, 0, 0};
                if (m < M) av = *(const bf16x8*)(A + (size_t)m * HC + kn + col);
                ra[s] = av;
                rb[s] = *(const bf16x8*)(Wt + (size_t)(o0 + row) * HC + kn + col);
            }
        }

#pragma unroll
        for (int kk = 0; kk < 2; kk++) {
            int kb = kk * 32 + (lane >> 4) * 8;
            bf16x8 af[4], bfr[8];
#pragma unroll
            for (int mi = 0; mi < 4; mi++)
                af[mi] = *(const bf16x8*)(&As[(wm * 64 + mi * 16 + (lane & 15)) * LDK + kb]);
#pragma unroll
            for (int ni = 0; ni < 8; ni++)
                bfr[ni] = *(const bf16x8*)(&Bs[(wn * 128 + ni * 16 + (lane & 15)) * LDK + kb]);
#pragma unroll
            for (int mi = 0; mi < 4; mi++)
#pragma unroll
                for (int ni = 0; ni < 8; ni++)
                    acc[mi][ni] = __builtin_amdgcn_mfma_f32_16x16x32_bf16(
                        af[mi], bfr[ni], acc[mi][ni], 0, 0, 0);
        }
    }

#pragma unroll
    for (int ni = 0; ni < 8; ni++) {
        int ncol = o0 + wn * 128 + ni * 16 + (lane & 15);
        float bv = bias[ncol];
#pragma unroll
        for (int mi = 0; mi < 4; mi++) {
            int mbase = m0 + wm * 64 + mi * 16 + (lane >> 4) * 4;
#pragma unroll
            for (int r = 0; r < 4; r++) {
                int m = mbase + r;
                if (m < M) {
                    float v = acc[mi][ni][r] + bv;
                    if (RELU) v = fmaxf(v, 0.f);
                    C[(size_t)m * HC + ncol] = f2bf(v);
                }
            }
        }
    }
}

// ---------------------------------------------------------------------------
// Final layer: out[m, 0..1] = tanh(h2[m] . W3[o] + b3[o]); one wave per row
// ---------------------------------------------------------------------------
__global__ void k_final(const unsigned short* __restrict__ h2, const float* __restrict__ W3,
                        const float* __restrict__ b3, float* __restrict__ out, int M) {
    int wave = threadIdx.x >> 6, lane = threadIdx.x & 63;
    int m = blockIdx.x * 4 + wave;
    if (m >= M) return;
    float s0 = 0.f, s1 = 0.f;
    bf16x8 hv = *(const bf16x8*)(h2 + (size_t)m * HC + lane * 8);
#pragma unroll
    for (int j = 0; j < 8; j++) {
        int k = lane * 8 + j;
        float v = bf2f((unsigned short)hv[j]);
        s0 += v * W3[k];
        s1 += v * W3[HC + k];
    }
#pragma unroll
    for (int off = 32; off >= 1; off >>= 1) {
        s0 += __shfl_xor(s0, off);
        s1 += __shfl_xor(s1, off);
    }
    if (lane == 0) {
        out[(size_t)m * 2 + 0] = tanhf(s0 + b3[0]);
        out[(size_t)m * 2 + 1] = tanhf(s1 + b3[1]);
    }
}

// ---------------------------------------------------------------------------
extern "C" void kernel_launch(void* const* d_in, const int* in_sizes, int n_in,
                              void* d_out, int out_size, void* d_ws, size_t ws_size,
                              hipStream_t stream) {
    const float* x       = (const float*)d_in[0];
    const int*   ei      = (const int*)d_in[1];
    const float* W       = (const float*)d_in[3];
    const float* att_src = (const float*)d_in[4];
    const float* att_dst = (const float*)d_in[5];
    const float* bias    = (const float*)d_in[6];
    const float* W1      = (const float*)d_in[7];
    const float* b1      = (const float*)d_in[8];
    const float* W2      = (const float*)d_in[9];
    const float* b2      = (const float*)d_in[10];
    const float* W3      = (const float*)d_in[11];
    const float* b3      = (const float*)d_in[12];
    float* out = (float*)d_out;

    char* ws = (char*)d_ws;
    unsigned short* h       = (unsigned short*)(ws);               // 51,200,000
    unsigned short* emb_sel = (unsigned short*)(ws + 51200000);    // 25,600,000
    unsigned short* h1      = (unsigned short*)(ws + 76800000);    // 25,600,000
    unsigned short* h2      = (unsigned short*)(ws + 102400000);   // 25,600,000
    unsigned short* W1b     = (unsigned short*)(ws + 128000000);   //    524,288
    unsigned short* W2b     = (unsigned short*)(ws + 128524288);   //    524,288
    float* a_src = (float*)(ws + 129048576);                       //    800,000
    float* a_dst = (float*)(ws + 129848576);                       //    800,000
    int*   deg   = (int*)  (ws + 130648576);                       //    200,000
    int*   offs  = (int*)  (ws + 130848576);                       //    200,000
    int*   curs  = (int*)  (ws + 131048576);                       //    200,000
    int*   csr   = (int*)  (ws + 131248576);                       //  1,800,000  (~133 MB)

    k_cvt2<<<512, 256, 0, stream>>>(W1, W2, W1b, W2b);
    k_transform<<<(N_NODES + 31) / 32, 256, 0, stream>>>(x, W, att_src, att_dst, h,
                                                         a_src, a_dst, deg);
    k_hist<<<(N_EDGES + 255) / 256, 256, 0, stream>>>(ei, deg);
    k_scanfill<<<1, 1024, 0, stream>>>(deg, offs, curs, csr);
    k_fill_edges<<<(N_EDGES + 255) / 256, 256, 0, stream>>>(ei, curs, csr);
    k_aggregate<<<6250, 256, 0, stream>>>(h, a_src, a_dst, csr, offs, deg, bias, emb_sel);

    dim3 g(2, 98);
    k_gemm<true><<<g, 512, 0, stream>>>(emb_sel, M_SEL, W1b, b1, h1);
    k_gemm<true><<<g, 512, 0, stream>>>(h1, M_SEL, W2b, b2, h2);
    k_final<<<(M_SEL + 3) / 4, 256, 0, stream>>>(h2, W3, b3, out, M_SEL);
}

// Round 5
// 216.115 us; speedup vs baseline: 1.4730x; 1.4730x over previous
//
#include <hip/hip_runtime.h>
#include <hip/hip_bf16.h>
#include <math.h>

#define N_NODES 50000
#define N_EDGES 400000
#define HEADS   4
#define HC      512
#define IN_DIM  5
#define M_SEL   25000
#define NEG_SLOPE 0.2f

typedef __attribute__((ext_vector_type(8))) short bf16x8;
typedef __attribute__((ext_vector_type(4))) float f32x4;

__device__ inline unsigned short f2bf(float f) {
    union { float f; unsigned u; } v; v.f = f;
    unsigned r = v.u + 0x7FFF + ((v.u >> 16) & 1);   // RNE
    return (unsigned short)(r >> 16);
}
__device__ inline float bf2f(unsigned short b) {
    union { unsigned u; float f; } v; v.u = ((unsigned)b) << 16;
    return v.f;
}

// ---------------------------------------------------------------------------
// fp32 -> bf16 conversion for W1 and W2 in one launch (2 x 65536 float4)
// ---------------------------------------------------------------------------
__global__ void k_cvt2(const float* __restrict__ W1, const float* __restrict__ W2,
                       unsigned short* __restrict__ W1b, unsigned short* __restrict__ W2b) {
    int i = blockIdx.x * 256 + threadIdx.x;
    const float* src = (i < 65536) ? W1 : W2;
    unsigned short* dst = (i < 65536) ? W1b : W2b;
    int j = i & 65535;
    float4 v = ((const float4*)src)[j];
    ushort4 o;
    o.x = f2bf(v.x); o.y = f2bf(v.y); o.z = f2bf(v.z); o.w = f2bf(v.w);
    ((ushort4*)dst)[j] = o;
}

// ---------------------------------------------------------------------------
// Kernel 1: h = x @ W.T (bf16); a_src/a_dst einsum [N,4] f32; deg init to 1.
// Register-resident weights (160B contiguous per lane), 8 nodes per wave.
// ---------------------------------------------------------------------------
#define TR_NPW 8

__global__ __launch_bounds__(256) void k_transform(
        const float* __restrict__ x, const float* __restrict__ W,
        const float* __restrict__ att_src, const float* __restrict__ att_dst,
        unsigned short* __restrict__ h, float* __restrict__ a_src,
        float* __restrict__ a_dst, int* __restrict__ deg) {
    int wave = threadIdx.x >> 6, lane = threadIdx.x & 63;
    int c0 = lane * 8;

    float wreg[40];
    const float4* wp = (const float4*)(W + c0 * IN_DIM);
#pragma unroll
    for (int i = 0; i < 10; i++) ((float4*)wreg)[i] = wp[i];
    float sas[8], sad[8];
    *(float4*)&sas[0] = *(const float4*)(att_src + c0);
    *(float4*)&sas[4] = *(const float4*)(att_src + c0 + 4);
    *(float4*)&sad[0] = *(const float4*)(att_dst + c0);
    *(float4*)&sad[4] = *(const float4*)(att_dst + c0 + 4);

    int n0 = (blockIdx.x * 4 + wave) * TR_NPW;
#pragma unroll
    for (int t = 0; t < TR_NPW; t++) {
        int n = n0 + t;
        if (n >= N_NODES) return;
        float xv[IN_DIM];
#pragma unroll
        for (int i = 0; i < IN_DIM; i++) xv[i] = x[n * IN_DIM + i];

        float ps = 0.f, pd = 0.f;
        bf16x8 hv8;
#pragma unroll
        for (int j = 0; j < 8; j++) {
            float acc = 0.f;
#pragma unroll
            for (int i = 0; i < IN_DIM; i++) acc += xv[i] * wreg[j * IN_DIM + i];
            hv8[j] = (short)f2bf(acc);
            ps += acc * sas[j];
            pd += acc * sad[j];
        }
        *(bf16x8*)(h + (size_t)n * HC + c0) = hv8;

#pragma unroll
        for (int off = 8; off >= 1; off >>= 1) {
            ps += __shfl_xor(ps, off);
            pd += __shfl_xor(pd, off);
        }
        if ((lane & 15) == 0) {
            int head = lane >> 4;
            a_src[n * HEADS + head] = ps;
            a_dst[n * HEADS + head] = pd;
        }
        if (lane == 0) deg[n] = 1;   // self-loop base for histogram
    }
}

// ---------------------------------------------------------------------------
// CSR build (multi-block scan; R4's single-block k_scanfill was 133 us)
// ---------------------------------------------------------------------------
__global__ void k_hist(const int* __restrict__ ei, int* __restrict__ deg) {
    int e = blockIdx.x * 256 + threadIdx.x;
    if (e < N_EDGES) atomicAdd(&deg[ei[N_EDGES + e]], 1);
}

__global__ void k_scan1(const int* __restrict__ deg, int* __restrict__ excl,
                        int* __restrict__ bsum) {
    __shared__ int s[256];
    int i = blockIdx.x * 256 + threadIdx.x;
    int v = (i < N_NODES) ? deg[i] : 0;
    s[threadIdx.x] = v;
    __syncthreads();
    for (int off = 1; off < 256; off <<= 1) {
        int t = (threadIdx.x >= off) ? s[threadIdx.x - off] : 0;
        __syncthreads();
        s[threadIdx.x] += t;
        __syncthreads();
    }
    if (i < N_NODES) excl[i] = s[threadIdx.x] - v;
    if (threadIdx.x == 255) bsum[blockIdx.x] = s[255];
}

__global__ void k_scan2(int* __restrict__ bsum, int nb) {
    if (threadIdx.x == 0 && blockIdx.x == 0) {
        int acc = 0;
        for (int b = 0; b < nb; b++) { int v = bsum[b]; bsum[b] = acc; acc += v; }
    }
}

// add block offset; write offs, self-loop csr slot, cursor
__global__ void k_scan3fill(int* __restrict__ excl, const int* __restrict__ bsum,
                            int* __restrict__ offs, int* __restrict__ curs,
                            int* __restrict__ csr) {
    int i = blockIdx.x * 256 + threadIdx.x;
    if (i < N_NODES) {
        int o = excl[i] + bsum[blockIdx.x];
        offs[i] = o;
        csr[o] = i;          // self loop in slot 0
        curs[i] = o + 1;
    }
}

__global__ void k_fill_edges(const int* __restrict__ ei, int* __restrict__ cursor,
                             int* __restrict__ csr) {
    int e = blockIdx.x * 256 + threadIdx.x;
    if (e < N_EDGES) {
        int d = ei[N_EDGES + e];
        int pos = atomicAdd(&cursor[d], 1);
        csr[pos] = ei[e];
    }
}

// ---------------------------------------------------------------------------
// Aggregate — TEAM NODES ONLY, one wave per dst node.
// Fast path (dn<=16, ~99.2%): single pass; lane (lane&15) owns one edge's
// logit for head (lane>>4); shuffle-reduced softmax; 4x-unrolled gather.
// ---------------------------------------------------------------------------
__global__ void k_aggregate(const unsigned short* __restrict__ h, const float* __restrict__ a_src,
                            const float* __restrict__ a_dst, const int* __restrict__ csr,
                            const int* __restrict__ offs, const int* __restrict__ deg,
                            const float* __restrict__ bias, unsigned short* __restrict__ emb_sel) {
    int wave = threadIdx.x >> 6, lane = threadIdx.x & 63;
    int w = blockIdx.x * 4 + wave;
    if (w >= M_SEL) return;
    int n = ((w >> 2) << 3) + (w & 3);   // TEAM_IDX[w]

    int base = offs[n];
    int dn = deg[n];
    int head = lane >> 4, egrp = lane & 15;
    float adn = a_dst[n * HEADS + head];
    int c0 = lane * 8;

    float acc[8];
#pragma unroll
    for (int j = 0; j < 8; j++) acc[j] = -INFINITY;

    if (dn <= 16) {
        int s_e = 0;
        float t = -INFINITY;
        if (egrp < dn) {
            s_e = csr[base + egrp];
            t = a_src[s_e * HEADS + head] + adn;
            t = (t > 0.f) ? t : NEG_SLOPE * t;
        }
        float m = t;
#pragma unroll
        for (int off = 8; off >= 1; off >>= 1) m = fmaxf(m, __shfl_xor(m, off));
        float ex = (egrp < dn) ? __expf(t - m) : 0.f;
        float den = ex;
#pragma unroll
        for (int off = 8; off >= 1; off >>= 1) den += __shfl_xor(den, off);
        float attn = ex / den;   // this lane's edge attn (for its head)

        int e = 0;
        for (; e + 4 <= dn; e += 4) {
            int s0 = __shfl(s_e, e + 0), s1 = __shfl(s_e, e + 1);
            int s2 = __shfl(s_e, e + 2), s3 = __shfl(s_e, e + 3);
            float a0 = __shfl(attn, (head << 4) | (e + 0));
            float a1 = __shfl(attn, (head << 4) | (e + 1));
            float a2 = __shfl(attn, (head << 4) | (e + 2));
            float a3 = __shfl(attn, (head << 4) | (e + 3));
            bf16x8 v0 = *(const bf16x8*)(h + (size_t)s0 * HC + c0);
            bf16x8 v1 = *(const bf16x8*)(h + (size_t)s1 * HC + c0);
            bf16x8 v2 = *(const bf16x8*)(h + (size_t)s2 * HC + c0);
            bf16x8 v3 = *(const bf16x8*)(h + (size_t)s3 * HC + c0);
#pragma unroll
            for (int j = 0; j < 8; j++) {
                acc[j] = fmaxf(acc[j], bf2f((unsigned short)v0[j]) * a0);
                acc[j] = fmaxf(acc[j], bf2f((unsigned short)v1[j]) * a1);
                acc[j] = fmaxf(acc[j], bf2f((unsigned short)v2[j]) * a2);
                acc[j] = fmaxf(acc[j], bf2f((unsigned short)v3[j]) * a3);
            }
        }
        for (; e < dn; e++) {
            int s = __shfl(s_e, e);
            float a = __shfl(attn, (head << 4) | e);
            bf16x8 v = *(const bf16x8*)(h + (size_t)s * HC + c0);
#pragma unroll
            for (int j = 0; j < 8; j++)
                acc[j] = fmaxf(acc[j], bf2f((unsigned short)v[j]) * a);
        }
    } else {
        // fallback: 3-pass (rare, dn>16)
        float m = -INFINITY;
        for (int e0 = 0; e0 < dn; e0 += 16) {
            int e = e0 + egrp;
            if (e < dn) {
                int s = csr[base + e];
                float t = a_src[s * HEADS + head] + adn;
                t = (t > 0.f) ? t : NEG_SLOPE * t;
                m = fmaxf(m, t);
            }
        }
#pragma unroll
        for (int off = 8; off >= 1; off >>= 1) m = fmaxf(m, __shfl_xor(m, off));
        float den = 0.f;
        for (int e0 = 0; e0 < dn; e0 += 16) {
            int e = e0 + egrp;
            if (e < dn) {
                int s = csr[base + e];
                float t = a_src[s * HEADS + head] + adn;
                t = (t > 0.f) ? t : NEG_SLOPE * t;
                den += __expf(t - m);
            }
        }
#pragma unroll
        for (int off = 8; off >= 1; off >>= 1) den += __shfl_xor(den, off);
        float invden = 1.0f / den;
        for (int e = 0; e < dn; e++) {
            int s = csr[base + e];
            float t = a_src[s * HEADS + head] + adn;
            t = (t > 0.f) ? t : NEG_SLOPE * t;
            float attn = __expf(t - m) * invden;
            bf16x8 hv = *(const bf16x8*)(h + (size_t)s * HC + c0);
#pragma unroll
            for (int j = 0; j < 8; j++)
                acc[j] = fmaxf(acc[j], bf2f((unsigned short)hv[j]) * attn);
        }
    }

    bf16x8 ov;
#pragma unroll
    for (int j = 0; j < 8; j++) ov[j] = (short)f2bf(acc[j] + bias[c0 + j]);
    *(bf16x8*)(emb_sel + (size_t)w * HC + c0) = ov;
}

// ---------------------------------------------------------------------------
// bf16 MFMA GEMM:  C[m,o] = relu( sum_k A[m,k]*Wt[o,k] + bias[o] ) -> bf16
// 256x256 tile, BK=64, 512 threads (4m x 2n waves, 64x128/wave).
// LDS rows padded to 72 shorts. Register-staged prefetch.
// ---------------------------------------------------------------------------
#define BK  64
#define LDK 72

template <bool RELU>
__global__ __launch_bounds__(512, 2) void k_gemm(const unsigned short* __restrict__ A, int M,
                                                 const unsigned short* __restrict__ Wt,
                                                 const float* __restrict__ bias,
                                                 unsigned short* __restrict__ C) {
    __shared__ unsigned short As[256 * LDK];
    __shared__ unsigned short Bs[256 * LDK];
    int tid = threadIdx.x;
    int m0 = blockIdx.y * 256;
    int o0 = blockIdx.x * 256;
    int wv = tid >> 6, lane = tid & 63;
    int wm = wv >> 1, wn = wv & 1;   // 4 x 2 wave grid

    f32x4 acc[4][8];
#pragma unroll
    for (int i = 0; i < 4; i++)
#pragma unroll
        for (int j = 0; j < 8; j++) acc[i][j] = (f32x4){0.f, 0.f, 0.f, 0.f};

    bf16x8 ra[4], rb[4];
#pragma unroll
    for (int s = 0; s < 4; s++) {
        int c = s * 512 + tid;           // 0..2047
        int row = c >> 3, col = (c & 7) * 8;
        int m = m0 + row;
        bf16x8 av = {0, 0, 0, 0, 0, 0, 0, 0};
        if (m < M) av = *(const bf16x8*)(A + (size_t)m * HC + col);
        ra[s] = av;
        rb[s] = *(const bf16x8*)(Wt + (size_t)(o0 + row) * HC + col);
    }

    for (int k0 = 0; k0 < HC; k0 += BK) {
        __syncthreads();
#pragma unroll
        for (int s = 0; s < 4; s++) {
            int c = s * 512 + tid;
            int row = c >> 3, col = (c & 7) * 8;
            *(bf16x8*)(&As[row * LDK + col]) = ra[s];
            *(bf16x8*)(&Bs[row * LDK + col]) = rb[s];
        }
        __syncthreads();

        int kn = k0 + BK;
        if (kn < HC) {
#pragma unroll
            for (int s = 0; s < 4; s++) {
                int c = s * 512 + tid;
                int row = c >> 3, col = (c & 7) * 8;
                int m = m0 + row;
                bf16x8 av = {0, 0, 0, 0, 0, 0, 0, 0};
                if (m < M) av = *(const bf16x8*)(A + (size_t)m * HC + kn + col);
                ra[s] = av;
                rb[s] = *(const bf16x8*)(Wt + (size_t)(o0 + row) * HC + kn + col);
            }
        }

#pragma unroll
        for (int kk = 0; kk < 2; kk++) {
            int kb = kk * 32 + (lane >> 4) * 8;
            bf16x8 af[4], bfr[8];
#pragma unroll
            for (int mi = 0; mi < 4; mi++)
                af[mi] = *(const bf16x8*)(&As[(wm * 64 + mi * 16 + (lane & 15)) * LDK + kb]);
#pragma unroll
            for (int ni = 0; ni < 8; ni++)
                bfr[ni] = *(const bf16x8*)(&Bs[(wn * 128 + ni * 16 + (lane & 15)) * LDK + kb]);
#pragma unroll
            for (int mi = 0; mi < 4; mi++)
#pragma unroll
                for (int ni = 0; ni < 8; ni++)
                    acc[mi][ni] = __builtin_amdgcn_mfma_f32_16x16x32_bf16(
                        af[mi], bfr[ni], acc[mi][ni], 0, 0, 0);
        }
    }

#pragma unroll
    for (int ni = 0; ni < 8; ni++) {
        int ncol = o0 + wn * 128 + ni * 16 + (lane & 15);
        float bv = bias[ncol];
#pragma unroll
        for (int mi = 0; mi < 4; mi++) {
            int mbase = m0 + wm * 64 + mi * 16 + (lane >> 4) * 4;
#pragma unroll
            for (int r = 0; r < 4; r++) {
                int m = mbase + r;
                if (m < M) {
                    float v = acc[mi][ni][r] + bv;
                    if (RELU) v = fmaxf(v, 0.f);
                    C[(size_t)m * HC + ncol] = f2bf(v);
                }
            }
        }
    }
}

// ---------------------------------------------------------------------------
// Final layer: out[m, 0..1] = tanh(h2[m] . W3[o] + b3[o]); one wave per row
// ---------------------------------------------------------------------------
__global__ void k_final(const unsigned short* __restrict__ h2, const float* __restrict__ W3,
                        const float* __restrict__ b3, float* __restrict__ out, int M) {
    int wave = threadIdx.x >> 6, lane = threadIdx.x & 63;
    int m = blockIdx.x * 4 + wave;
    if (m >= M) return;
    float s0 = 0.f, s1 = 0.f;
    bf16x8 hv = *(const bf16x8*)(h2 + (size_t)m * HC + lane * 8);
#pragma unroll
    for (int j = 0; j < 8; j++) {
        int k = lane * 8 + j;
        float v = bf2f((unsigned short)hv[j]);
        s0 += v * W3[k];
        s1 += v * W3[HC + k];
    }
#pragma unroll
    for (int off = 32; off >= 1; off >>= 1) {
        s0 += __shfl_xor(s0, off);
        s1 += __shfl_xor(s1, off);
    }
    if (lane == 0) {
        out[(size_t)m * 2 + 0] = tanhf(s0 + b3[0]);
        out[(size_t)m * 2 + 1] = tanhf(s1 + b3[1]);
    }
}

// ---------------------------------------------------------------------------
extern "C" void kernel_launch(void* const* d_in, const int* in_sizes, int n_in,
                              void* d_out, int out_size, void* d_ws, size_t ws_size,
                              hipStream_t stream) {
    const float* x       = (const float*)d_in[0];
    const int*   ei      = (const int*)d_in[1];
    const float* W       = (const float*)d_in[3];
    const float* att_src = (const float*)d_in[4];
    const float* att_dst = (const float*)d_in[5];
    const float* bias    = (const float*)d_in[6];
    const float* W1      = (const float*)d_in[7];
    const float* b1      = (const float*)d_in[8];
    const float* W2      = (const float*)d_in[9];
    const float* b2      = (const float*)d_in[10];
    const float* W3      = (const float*)d_in[11];
    const float* b3      = (const float*)d_in[12];
    float* out = (float*)d_out;

    char* ws = (char*)d_ws;
    unsigned short* h       = (unsigned short*)(ws);               // 51,200,000
    unsigned short* emb_sel = (unsigned short*)(ws + 51200000);    // 25,600,000
    unsigned short* h1      = (unsigned short*)(ws + 76800000);    // 25,600,000
    unsigned short* h2      = (unsigned short*)(ws + 102400000);   // 25,600,000
    unsigned short* W1b     = (unsigned short*)(ws + 128000000);   //    524,288
    unsigned short* W2b     = (unsigned short*)(ws + 128524288);   //    524,288
    float* a_src = (float*)(ws + 129048576);                       //    800,000
    float* a_dst = (float*)(ws + 129848576);                       //    800,000
    int*   deg   = (int*)  (ws + 130648576);                       //    200,000
    int*   offs  = (int*)  (ws + 130848576);                       //    200,000
    int*   curs  = (int*)  (ws + 131048576);                       //    200,000
    int*   excl  = (int*)  (ws + 131248576);                       //    200,000
    int*   bsum  = (int*)  (ws + 131448576);                       //      1,024
    int*   csr   = (int*)  (ws + 131449600);                       //  1,800,000  (~133 MB)

    k_cvt2<<<512, 256, 0, stream>>>(W1, W2, W1b, W2b);
    k_transform<<<(N_NODES + 31) / 32, 256, 0, stream>>>(x, W, att_src, att_dst, h,
                                                         a_src, a_dst, deg);
    k_hist<<<(N_EDGES + 255) / 256, 256, 0, stream>>>(ei, deg);
    k_scan1<<<196, 256, 0, stream>>>(deg, excl, bsum);
    k_scan2<<<1, 64, 0, stream>>>(bsum, 196);
    k_scan3fill<<<196, 256, 0, stream>>>(excl, bsum, offs, curs, csr);
    k_fill_edges<<<(N_EDGES + 255) / 256, 256, 0, stream>>>(ei, curs, csr);
    k_aggregate<<<6250, 256, 0, stream>>>(h, a_src, a_dst, csr, offs, deg, bias, emb_sel);

    dim3 g(2, 98);
    k_gemm<true><<<g, 512, 0, stream>>>(emb_sel, M_SEL, W1b, b1, h1);
    k_gemm<true><<<g, 512, 0, stream>>>(h1, M_SEL, W2b, b2, h2);
    k_final<<<(M_SEL + 3) / 4, 256, 0, stream>>>(h2, W3, b3, out, M_SEL);
}

// Round 6
// 208.779 us; speedup vs baseline: 1.5248x; 1.0351x over previous
//
#include <hip/hip_runtime.h>
#include <hip/hip_bf16.h>
#include <math.h>

#define N_NODES 50000
#define N_EDGES 400000
#define HEADS   4
#define HC      512
#define IN_DIM  5
#define M_SEL   25000
#define NEG_SLOPE 0.2f

typedef __attribute__((ext_vector_type(8))) short bf16x8;
typedef __attribute__((ext_vector_type(4))) float f32x4;

__device__ inline unsigned short f2bf(float f) {
    union { float f; unsigned u; } v; v.f = f;
    unsigned r = v.u + 0x7FFF + ((v.u >> 16) & 1);   // RNE
    return (unsigned short)(r >> 16);
}
__device__ inline float bf2f(unsigned short b) {
    union { unsigned u; float f; } v; v.u = ((unsigned)b) << 16;
    return v.f;
}

// ---------------------------------------------------------------------------
// Kernel 1: h = x @ W.T (bf16); a_src/a_dst einsum [N,4] f32; deg init to 1.
// Register-resident weights (160B contiguous per lane), 8 nodes per wave.
// ---------------------------------------------------------------------------
#define TR_NPW 8

__global__ __launch_bounds__(256) void k_transform(
        const float* __restrict__ x, const float* __restrict__ W,
        const float* __restrict__ att_src, const float* __restrict__ att_dst,
        unsigned short* __restrict__ h, float* __restrict__ a_src,
        float* __restrict__ a_dst, int* __restrict__ deg) {
    int wave = threadIdx.x >> 6, lane = threadIdx.x & 63;
    int c0 = lane * 8;

    float wreg[40];
    const float4* wp = (const float4*)(W + c0 * IN_DIM);
#pragma unroll
    for (int i = 0; i < 10; i++) ((float4*)wreg)[i] = wp[i];
    float sas[8], sad[8];
    *(float4*)&sas[0] = *(const float4*)(att_src + c0);
    *(float4*)&sas[4] = *(const float4*)(att_src + c0 + 4);
    *(float4*)&sad[0] = *(const float4*)(att_dst + c0);
    *(float4*)&sad[4] = *(const float4*)(att_dst + c0 + 4);

    int n0 = (blockIdx.x * 4 + wave) * TR_NPW;
#pragma unroll
    for (int t = 0; t < TR_NPW; t++) {
        int n = n0 + t;
        if (n >= N_NODES) return;
        float xv[IN_DIM];
#pragma unroll
        for (int i = 0; i < IN_DIM; i++) xv[i] = x[n * IN_DIM + i];

        float ps = 0.f, pd = 0.f;
        bf16x8 hv8;
#pragma unroll
        for (int j = 0; j < 8; j++) {
            float acc = 0.f;
#pragma unroll
            for (int i = 0; i < IN_DIM; i++) acc += xv[i] * wreg[j * IN_DIM + i];
            hv8[j] = (short)f2bf(acc);
            ps += acc * sas[j];
            pd += acc * sad[j];
        }
        *(bf16x8*)(h + (size_t)n * HC + c0) = hv8;

#pragma unroll
        for (int off = 8; off >= 1; off >>= 1) {
            ps += __shfl_xor(ps, off);
            pd += __shfl_xor(pd, off);
        }
        if ((lane & 15) == 0) {
            int head = lane >> 4;
            a_src[n * HEADS + head] = ps;
            a_dst[n * HEADS + head] = pd;
        }
        if (lane == 0) deg[n] = 1;   // self-loop base for histogram
    }
}

// ---------------------------------------------------------------------------
// CSR build (multi-block; R4 lesson: never single-block the scan)
// ---------------------------------------------------------------------------
__global__ void k_hist(const int* __restrict__ ei, int* __restrict__ deg) {
    int e = blockIdx.x * 256 + threadIdx.x;
    if (e < N_EDGES) atomicAdd(&deg[ei[N_EDGES + e]], 1);
}

#define NSCAN_BLK 196

__global__ void k_scan1(const int* __restrict__ deg, int* __restrict__ excl,
                        int* __restrict__ bsum) {
    __shared__ int s[256];
    int i = blockIdx.x * 256 + threadIdx.x;
    int v = (i < N_NODES) ? deg[i] : 0;
    s[threadIdx.x] = v;
    __syncthreads();
    for (int off = 1; off < 256; off <<= 1) {
        int t = (threadIdx.x >= off) ? s[threadIdx.x - off] : 0;
        __syncthreads();
        s[threadIdx.x] += t;
        __syncthreads();
    }
    if (i < N_NODES) excl[i] = s[threadIdx.x] - v;
    if (threadIdx.x == 255) bsum[blockIdx.x] = s[255];
}

// each block redundantly scans the 196 block sums (784B, L2-hot), then
// writes offs, self-loop csr slot, and cursor
__global__ void k_scan3fill(const int* __restrict__ excl, const int* __restrict__ bsum,
                            int* __restrict__ offs, int* __restrict__ curs,
                            int* __restrict__ csr) {
    __shared__ int part[256];
    int tid = threadIdx.x;
    part[tid] = (tid < NSCAN_BLK) ? bsum[tid] : 0;
    __syncthreads();
    for (int off = 1; off < 256; off <<= 1) {
        int t = (tid >= off) ? part[tid - off] : 0;
        __syncthreads();
        part[tid] += t;
        __syncthreads();
    }
    int blockoff = (blockIdx.x == 0) ? 0 : part[blockIdx.x - 1];
    int i = blockIdx.x * 256 + tid;
    if (i < N_NODES) {
        int o = excl[i] + blockoff;
        offs[i] = o;
        csr[o] = i;          // self loop in slot 0
        curs[i] = o + 1;
    }
}

__global__ void k_fill_edges(const int* __restrict__ ei, int* __restrict__ cursor,
                             int* __restrict__ csr) {
    int e = blockIdx.x * 256 + threadIdx.x;
    if (e < N_EDGES) {
        int d = ei[N_EDGES + e];
        int pos = atomicAdd(&cursor[d], 1);
        csr[pos] = ei[e];
    }
}

// ---------------------------------------------------------------------------
// Aggregate — TEAM NODES ONLY, one wave per dst node.
// Fast path (dn<=16, ~99.2%): issue ALL dn 1KB row-gathers FIRST (16KB in
// flight per wave), then do the softmax chain under the load latency, then
// consume. All v[] indices compile-time (unrolled + wave-uniform predicate).
// ---------------------------------------------------------------------------
__global__ void k_aggregate(const unsigned short* __restrict__ h, const float* __restrict__ a_src,
                            const float* __restrict__ a_dst, const int* __restrict__ csr,
                            const int* __restrict__ offs, const int* __restrict__ deg,
                            const float* __restrict__ bias, unsigned short* __restrict__ emb_sel) {
    int wave = threadIdx.x >> 6, lane = threadIdx.x & 63;
    int w = blockIdx.x * 4 + wave;
    if (w >= M_SEL) return;
    int n = ((w >> 2) << 3) + (w & 3);   // TEAM_IDX[w]

    int base = offs[n];
    int dn = deg[n];
    int head = lane >> 4, egrp = lane & 15;
    int c0 = lane * 8;

    float acc[8];
#pragma unroll
    for (int j = 0; j < 8; j++) acc[j] = -INFINITY;

    if (dn <= 16) {
        int s_e = 0;
        if (egrp < dn) s_e = csr[base + egrp];

        // issue all gathers first (indices via wave shuffle, loads in flight)
        bf16x8 v[16];
#pragma unroll
        for (int e = 0; e < 16; e++) {
            if (e < dn) {
                int s = __shfl(s_e, e);
                v[e] = *(const bf16x8*)(h + (size_t)s * HC + c0);
            }
        }

        // softmax chain overlaps gather latency
        float adn = a_dst[n * HEADS + head];
        float t = -INFINITY;
        if (egrp < dn) {
            t = a_src[s_e * HEADS + head] + adn;
            t = (t > 0.f) ? t : NEG_SLOPE * t;
        }
        float m = t;
#pragma unroll
        for (int off = 8; off >= 1; off >>= 1) m = fmaxf(m, __shfl_xor(m, off));
        float ex = (egrp < dn) ? __expf(t - m) : 0.f;
        float den = ex;
#pragma unroll
        for (int off = 8; off >= 1; off >>= 1) den += __shfl_xor(den, off);
        float attn = ex / den;   // this lane's edge attn (for its head)

        // consume
#pragma unroll
        for (int e = 0; e < 16; e++) {
            if (e < dn) {
                float a = __shfl(attn, (head << 4) | e);
#pragma unroll
                for (int j = 0; j < 8; j++)
                    acc[j] = fmaxf(acc[j], bf2f((unsigned short)v[e][j]) * a);
            }
        }
    } else {
        // fallback: 3-pass (rare, dn>16)
        float adn = a_dst[n * HEADS + head];
        float m = -INFINITY;
        for (int e0 = 0; e0 < dn; e0 += 16) {
            int e = e0 + egrp;
            if (e < dn) {
                int s = csr[base + e];
                float t = a_src[s * HEADS + head] + adn;
                t = (t > 0.f) ? t : NEG_SLOPE * t;
                m = fmaxf(m, t);
            }
        }
#pragma unroll
        for (int off = 8; off >= 1; off >>= 1) m = fmaxf(m, __shfl_xor(m, off));
        float den = 0.f;
        for (int e0 = 0; e0 < dn; e0 += 16) {
            int e = e0 + egrp;
            if (e < dn) {
                int s = csr[base + e];
                float t = a_src[s * HEADS + head] + adn;
                t = (t > 0.f) ? t : NEG_SLOPE * t;
                den += __expf(t - m);
            }
        }
#pragma unroll
        for (int off = 8; off >= 1; off >>= 1) den += __shfl_xor(den, off);
        float invden = 1.0f / den;
        for (int e = 0; e < dn; e++) {
            int s = csr[base + e];
            float t = a_src[s * HEADS + head] + adn;
            t = (t > 0.f) ? t : NEG_SLOPE * t;
            float attn = __expf(t - m) * invden;
            bf16x8 hv = *(const bf16x8*)(h + (size_t)s * HC + c0);
#pragma unroll
            for (int j = 0; j < 8; j++)
                acc[j] = fmaxf(acc[j], bf2f((unsigned short)hv[j]) * attn);
        }
    }

    bf16x8 ov;
#pragma unroll
    for (int j = 0; j < 8; j++) ov[j] = (short)f2bf(acc[j] + bias[c0 + j]);
    *(bf16x8*)(emb_sel + (size_t)w * HC + c0) = ov;
}

// ---------------------------------------------------------------------------
// bf16 MFMA GEMM:  C[m,o] = relu( sum_k A[m,k]*Wt[o,k] + bias[o] ) -> bf16
// A is bf16; Wt is fp32, converted to bf16 in registers during staging
// (removes the separate cvt kernel). 256x256 tile, BK=64, 512 threads
// (4m x 2n waves, 64x128/wave). LDS rows padded to 72 shorts (2-way = free).
// ---------------------------------------------------------------------------
#define BK  64
#define LDK 72

__device__ inline bf16x8 cvt8(float4 a, float4 b) {
    bf16x8 r;
    r[0] = (short)f2bf(a.x); r[1] = (short)f2bf(a.y);
    r[2] = (short)f2bf(a.z); r[3] = (short)f2bf(a.w);
    r[4] = (short)f2bf(b.x); r[5] = (short)f2bf(b.y);
    r[6] = (short)f2bf(b.z); r[7] = (short)f2bf(b.w);
    return r;
}

template <bool RELU>
__global__ __launch_bounds__(512, 2) void k_gemm(const unsigned short* __restrict__ A, int M,
                                                 const float* __restrict__ Wt,
                                                 const float* __restrict__ bias,
                                                 unsigned short* __restrict__ C) {
    __shared__ unsigned short As[256 * LDK];
    __shared__ unsigned short Bs[256 * LDK];
    int tid = threadIdx.x;
    int m0 = blockIdx.y * 256;
    int o0 = blockIdx.x * 256;
    int wv = tid >> 6, lane = tid & 63;
    int wm = wv >> 1, wn = wv & 1;   // 4 x 2 wave grid

    f32x4 acc[4][8];
#pragma unroll
    for (int i = 0; i < 4; i++)
#pragma unroll
        for (int j = 0; j < 8; j++) acc[i][j] = (f32x4){0.f, 0.f, 0.f, 0.f};

    bf16x8 ra[4], rb[4];
#pragma unroll
    for (int s = 0; s < 4; s++) {
        int c = s * 512 + tid;           // 0..2047
        int row = c >> 3, col = (c & 7) * 8;
        int m = m0 + row;
        bf16x8 av = {0, 0, 0, 0, 0, 0, 0, 0};
        if (m < M) av = *(const bf16x8*)(A + (size_t)m * HC + col);
        ra[s] = av;
        const float4* wp = (const float4*)(Wt + (size_t)(o0 + row) * HC + col);
        rb[s] = cvt8(wp[0], wp[1]);
    }

    for (int k0 = 0; k0 < HC; k0 += BK) {
        __syncthreads();
#pragma unroll
        for (int s = 0; s < 4; s++) {
            int c = s * 512 + tid;
            int row = c >> 3, col = (c & 7) * 8;
            *(bf16x8*)(&As[row * LDK + col]) = ra[s];
            *(bf16x8*)(&Bs[row * LDK + col]) = rb[s];
        }
        __syncthreads();

        int kn = k0 + BK;
        if (kn < HC) {
#pragma unroll
            for (int s = 0; s < 4; s++) {
                int c = s * 512 + tid;
                int row = c >> 3, col = (c & 7) * 8;
                int m = m0 + row;
                bf16x8 av = {0, 0, 0, 0, 0, 0, 0, 0};
                if (m < M) av = *(const bf16x8*)(A + (size_t)m * HC + kn + col);
                ra[s] = av;
                const float4* wp = (const float4*)(Wt + (size_t)(o0 + row) * HC + kn + col);
                rb[s] = cvt8(wp[0], wp[1]);
            }
        }

#pragma unroll
        for (int kk = 0; kk < 2; kk++) {
            int kb = kk * 32 + (lane >> 4) * 8;
            bf16x8 af[4], bfr[8];
#pragma unroll
            for (int mi = 0; mi < 4; mi++)
                af[mi] = *(const bf16x8*)(&As[(wm * 64 + mi * 16 + (lane & 15)) * LDK + kb]);
#pragma unroll
            for (int ni = 0; ni < 8; ni++)
                bfr[ni] = *(const bf16x8*)(&Bs[(wn * 128 + ni * 16 + (lane & 15)) * LDK + kb]);
#pragma unroll
            for (int mi = 0; mi < 4; mi++)
#pragma unroll
                for (int ni = 0; ni < 8; ni++)
                    acc[mi][ni] = __builtin_amdgcn_mfma_f32_16x16x32_bf16(
                        af[mi], bfr[ni], acc[mi][ni], 0, 0, 0);
        }
    }

#pragma unroll
    for (int ni = 0; ni < 8; ni++) {
        int ncol = o0 + wn * 128 + ni * 16 + (lane & 15);
        float bv = bias[ncol];
#pragma unroll
        for (int mi = 0; mi < 4; mi++) {
            int mbase = m0 + wm * 64 + mi * 16 + (lane >> 4) * 4;
#pragma unroll
            for (int r = 0; r < 4; r++) {
                int m = mbase + r;
                if (m < M) {
                    float v = acc[mi][ni][r] + bv;
                    if (RELU) v = fmaxf(v, 0.f);
                    C[(size_t)m * HC + ncol] = f2bf(v);
                }
            }
        }
    }
}

// ---------------------------------------------------------------------------
// Final layer: out[m, 0..1] = tanh(h2[m] . W3[o] + b3[o]); one wave per row
// ---------------------------------------------------------------------------
__global__ void k_final(const unsigned short* __restrict__ h2, const float* __restrict__ W3,
                        const float* __restrict__ b3, float* __restrict__ out, int M) {
    int wave = threadIdx.x >> 6, lane = threadIdx.x & 63;
    int m = blockIdx.x * 4 + wave;
    if (m >= M) return;
    float s0 = 0.f, s1 = 0.f;
    bf16x8 hv = *(const bf16x8*)(h2 + (size_t)m * HC + lane * 8);
#pragma unroll
    for (int j = 0; j < 8; j++) {
        int k = lane * 8 + j;
        float v = bf2f((unsigned short)hv[j]);
        s0 += v * W3[k];
        s1 += v * W3[HC + k];
    }
#pragma unroll
    for (int off = 32; off >= 1; off >>= 1) {
        s0 += __shfl_xor(s0, off);
        s1 += __shfl_xor(s1, off);
    }
    if (lane == 0) {
        out[(size_t)m * 2 + 0] = tanhf(s0 + b3[0]);
        out[(size_t)m * 2 + 1] = tanhf(s1 + b3[1]);
    }
}

// ---------------------------------------------------------------------------
extern "C" void kernel_launch(void* const* d_in, const int* in_sizes, int n_in,
                              void* d_out, int out_size, void* d_ws, size_t ws_size,
                              hipStream_t stream) {
    const float* x       = (const float*)d_in[0];
    const int*   ei      = (const int*)d_in[1];
    const float* W       = (const float*)d_in[3];
    const float* att_src = (const float*)d_in[4];
    const float* att_dst = (const float*)d_in[5];
    const float* bias    = (const float*)d_in[6];
    const float* W1      = (const float*)d_in[7];
    const float* b1      = (const float*)d_in[8];
    const float* W2      = (const float*)d_in[9];
    const float* b2      = (const float*)d_in[10];
    const float* W3      = (const float*)d_in[11];
    const float* b3      = (const float*)d_in[12];
    float* out = (float*)d_out;

    char* ws = (char*)d_ws;
    unsigned short* h       = (unsigned short*)(ws);               // 51,200,000
    unsigned short* emb_sel = (unsigned short*)(ws + 51200000);    // 25,600,000
    unsigned short* h1      = (unsigned short*)(ws + 76800000);    // 25,600,000
    unsigned short* h2      = (unsigned short*)(ws + 102400000);   // 25,600,000
    float* a_src = (float*)(ws + 129048576);                       //    800,000
    float* a_dst = (float*)(ws + 129848576);                       //    800,000
    int*   deg   = (int*)  (ws + 130648576);                       //    200,000
    int*   offs  = (int*)  (ws + 130848576);                       //    200,000
    int*   curs  = (int*)  (ws + 131048576);                       //    200,000
    int*   excl  = (int*)  (ws + 131248576);                       //    200,000
    int*   bsum  = (int*)  (ws + 131448576);                       //      1,024
    int*   csr   = (int*)  (ws + 131449600);                       //  1,800,000  (~133 MB)

    k_transform<<<(N_NODES + 31) / 32, 256, 0, stream>>>(x, W, att_src, att_dst, h,
                                                         a_src, a_dst, deg);
    k_hist<<<(N_EDGES + 255) / 256, 256, 0, stream>>>(ei, deg);
    k_scan1<<<NSCAN_BLK, 256, 0, stream>>>(deg, excl, bsum);
    k_scan3fill<<<NSCAN_BLK, 256, 0, stream>>>(excl, bsum, offs, curs, csr);
    k_fill_edges<<<(N_EDGES + 255) / 256, 256, 0, stream>>>(ei, curs, csr);
    k_aggregate<<<6250, 256, 0, stream>>>(h, a_src, a_dst, csr, offs, deg, bias, emb_sel);

    dim3 g(2, 98);
    k_gemm<true><<<g, 512, 0, stream>>>(emb_sel, M_SEL, W1, b1, h1);
    k_gemm<true><<<g, 512, 0, stream>>>(h1, M_SEL, W2, b2, h2);
    k_final<<<(M_SEL + 3) / 4, 256, 0, stream>>>(h2, W3, b3, out, M_SEL);
}

// Round 7
// 191.748 us; speedup vs baseline: 1.6602x; 1.0888x over previous
//
#include <hip/hip_runtime.h>
#include <hip/hip_bf16.h>
#include <math.h>

#define N_NODES 50000
#define N_EDGES 400000
#define HEADS   4
#define HC      512
#define IN_DIM  5
#define M_SEL   25000
#define NEG_SLOPE 0.2f

typedef __attribute__((ext_vector_type(8))) short bf16x8;
typedef __attribute__((ext_vector_type(4))) float f32x4;

__device__ inline unsigned short f2bf(float f) {
    union { float f; unsigned u; } v; v.f = f;
    unsigned r = v.u + 0x7FFF + ((v.u >> 16) & 1);   // RNE
    return (unsigned short)(r >> 16);
}
__device__ inline float bf2f(unsigned short b) {
    union { unsigned u; float f; } v; v.u = ((unsigned)b) << 16;
    return v.f;
}

// ---------------------------------------------------------------------------
// Kernel 1: h = x @ W.T (bf16); a_src/a_dst einsum [N,4] f32; deg init to 1.
// Register-resident weights (160B contiguous per lane), 8 nodes per wave.
// ---------------------------------------------------------------------------
#define TR_NPW 8

__global__ __launch_bounds__(256) void k_transform(
        const float* __restrict__ x, const float* __restrict__ W,
        const float* __restrict__ att_src, const float* __restrict__ att_dst,
        unsigned short* __restrict__ h, float* __restrict__ a_src,
        float* __restrict__ a_dst, int* __restrict__ deg) {
    int wave = threadIdx.x >> 6, lane = threadIdx.x & 63;
    int c0 = lane * 8;

    float wreg[40];
    const float4* wp = (const float4*)(W + c0 * IN_DIM);
#pragma unroll
    for (int i = 0; i < 10; i++) ((float4*)wreg)[i] = wp[i];
    float sas[8], sad[8];
    *(float4*)&sas[0] = *(const float4*)(att_src + c0);
    *(float4*)&sas[4] = *(const float4*)(att_src + c0 + 4);
    *(float4*)&sad[0] = *(const float4*)(att_dst + c0);
    *(float4*)&sad[4] = *(const float4*)(att_dst + c0 + 4);

    int n0 = (blockIdx.x * 4 + wave) * TR_NPW;
#pragma unroll
    for (int t = 0; t < TR_NPW; t++) {
        int n = n0 + t;
        if (n >= N_NODES) return;
        float xv[IN_DIM];
#pragma unroll
        for (int i = 0; i < IN_DIM; i++) xv[i] = x[n * IN_DIM + i];

        float ps = 0.f, pd = 0.f;
        bf16x8 hv8;
#pragma unroll
        for (int j = 0; j < 8; j++) {
            float acc = 0.f;
#pragma unroll
            for (int i = 0; i < IN_DIM; i++) acc += xv[i] * wreg[j * IN_DIM + i];
            hv8[j] = (short)f2bf(acc);
            ps += acc * sas[j];
            pd += acc * sad[j];
        }
        *(bf16x8*)(h + (size_t)n * HC + c0) = hv8;

#pragma unroll
        for (int off = 8; off >= 1; off >>= 1) {
            ps += __shfl_xor(ps, off);
            pd += __shfl_xor(pd, off);
        }
        if ((lane & 15) == 0) {
            int head = lane >> 4;
            a_src[n * HEADS + head] = ps;
            a_dst[n * HEADS + head] = pd;
        }
        if (lane == 0) deg[n] = 1;   // self-loop base for histogram
    }
}

// ---------------------------------------------------------------------------
// CSR build (multi-block; R4 lesson: never single-block the scan)
// ---------------------------------------------------------------------------
__global__ void k_hist(const int* __restrict__ ei, int* __restrict__ deg) {
    int e = blockIdx.x * 256 + threadIdx.x;
    if (e < N_EDGES) atomicAdd(&deg[ei[N_EDGES + e]], 1);
}

#define NSCAN_BLK 196

__global__ void k_scan1(const int* __restrict__ deg, int* __restrict__ excl,
                        int* __restrict__ bsum) {
    __shared__ int s[256];
    int i = blockIdx.x * 256 + threadIdx.x;
    int v = (i < N_NODES) ? deg[i] : 0;
    s[threadIdx.x] = v;
    __syncthreads();
    for (int off = 1; off < 256; off <<= 1) {
        int t = (threadIdx.x >= off) ? s[threadIdx.x - off] : 0;
        __syncthreads();
        s[threadIdx.x] += t;
        __syncthreads();
    }
    if (i < N_NODES) excl[i] = s[threadIdx.x] - v;
    if (threadIdx.x == 255) bsum[blockIdx.x] = s[255];
}

// each block redundantly scans the 196 block sums (784B, L2-hot), then
// writes offs, self-loop csr slot, and cursor
__global__ void k_scan3fill(const int* __restrict__ excl, const int* __restrict__ bsum,
                            int* __restrict__ offs, int* __restrict__ curs,
                            int* __restrict__ csr) {
    __shared__ int part[256];
    int tid = threadIdx.x;
    part[tid] = (tid < NSCAN_BLK) ? bsum[tid] : 0;
    __syncthreads();
    for (int off = 1; off < 256; off <<= 1) {
        int t = (tid >= off) ? part[tid - off] : 0;
        __syncthreads();
        part[tid] += t;
        __syncthreads();
    }
    int blockoff = (blockIdx.x == 0) ? 0 : part[blockIdx.x - 1];
    int i = blockIdx.x * 256 + tid;
    if (i < N_NODES) {
        int o = excl[i] + blockoff;
        offs[i] = o;
        csr[o] = i;          // self loop in slot 0
        curs[i] = o + 1;
    }
}

__global__ void k_fill_edges(const int* __restrict__ ei, int* __restrict__ cursor,
                             int* __restrict__ csr) {
    int e = blockIdx.x * 256 + threadIdx.x;
    if (e < N_EDGES) {
        int d = ei[N_EDGES + e];
        int pos = atomicAdd(&cursor[d], 1);
        csr[pos] = ei[e];
    }
}

// ---------------------------------------------------------------------------
// Aggregate — TEAM NODES ONLY, one wave per dst node.
// Fast path (dn<=16, ~99.2%): issue softmax scalar loads, then ALL row
// gathers; sched_barrier(0) fences the cluster so hipcc cannot sink the
// loads to their uses (R6 failure: VGPR=44 showed loads were serialized).
// Softmax chain then runs under gather latency; consume afterwards.
// ---------------------------------------------------------------------------
__global__ __launch_bounds__(256, 4) void k_aggregate(
        const unsigned short* __restrict__ h, const float* __restrict__ a_src,
        const float* __restrict__ a_dst, const int* __restrict__ csr,
        const int* __restrict__ offs, const int* __restrict__ deg,
        const float* __restrict__ bias, unsigned short* __restrict__ emb_sel) {
    int wave = threadIdx.x >> 6, lane = threadIdx.x & 63;
    int w = blockIdx.x * 4 + wave;
    if (w >= M_SEL) return;
    int n = ((w >> 2) << 3) + (w & 3);   // TEAM_IDX[w]

    int base = offs[n];
    int dn = deg[n];
    int head = lane >> 4, egrp = lane & 15;
    int c0 = lane * 8;

    float acc[8];
#pragma unroll
    for (int j = 0; j < 8; j++) acc[j] = -INFINITY;

    if (dn <= 16) {
        // latency loads for the softmax chain go first
        int s_e = 0;
        if (egrp < dn) s_e = csr[base + egrp];
        float adn = a_dst[n * HEADS + head];
        float araw = 0.f;
        if (egrp < dn) araw = a_src[s_e * HEADS + head];

        // issue all row gathers (up to 16KB in flight per wave)
        bf16x8 v[16];
#pragma unroll
        for (int e = 0; e < 16; e++) {
            if (e < dn) {                       // wave-uniform scalar branch
                int s = __shfl(s_e, e);
                v[e] = *(const bf16x8*)(h + (size_t)s * HC + c0);
            }
        }
        __builtin_amdgcn_sched_barrier(0);      // keep loads issued HERE

        // softmax (overlaps gather latency)
        float t = -INFINITY;
        if (egrp < dn) {
            t = araw + adn;
            t = (t > 0.f) ? t : NEG_SLOPE * t;
        }
        float m = t;
#pragma unroll
        for (int off = 8; off >= 1; off >>= 1) m = fmaxf(m, __shfl_xor(m, off));
        float ex = (egrp < dn) ? __expf(t - m) : 0.f;
        float den = ex;
#pragma unroll
        for (int off = 8; off >= 1; off >>= 1) den += __shfl_xor(den, off);
        float attn = ex / den;   // this lane's edge attn (for its head)

        // consume
#pragma unroll
        for (int e = 0; e < 16; e++) {
            if (e < dn) {
                float a = __shfl(attn, (head << 4) | e);
#pragma unroll
                for (int j = 0; j < 8; j++)
                    acc[j] = fmaxf(acc[j], bf2f((unsigned short)v[e][j]) * a);
            }
        }
    } else {
        // fallback: 3-pass (rare, dn>16)
        float adn = a_dst[n * HEADS + head];
        float m = -INFINITY;
        for (int e0 = 0; e0 < dn; e0 += 16) {
            int e = e0 + egrp;
            if (e < dn) {
                int s = csr[base + e];
                float t = a_src[s * HEADS + head] + adn;
                t = (t > 0.f) ? t : NEG_SLOPE * t;
                m = fmaxf(m, t);
            }
        }
#pragma unroll
        for (int off = 8; off >= 1; off >>= 1) m = fmaxf(m, __shfl_xor(m, off));
        float den = 0.f;
        for (int e0 = 0; e0 < dn; e0 += 16) {
            int e = e0 + egrp;
            if (e < dn) {
                int s = csr[base + e];
                float t = a_src[s * HEADS + head] + adn;
                t = (t > 0.f) ? t : NEG_SLOPE * t;
                den += __expf(t - m);
            }
        }
#pragma unroll
        for (int off = 8; off >= 1; off >>= 1) den += __shfl_xor(den, off);
        float invden = 1.0f / den;
        for (int e = 0; e < dn; e++) {
            int s = csr[base + e];
            float t = a_src[s * HEADS + head] + adn;
            t = (t > 0.f) ? t : NEG_SLOPE * t;
            float attn = __expf(t - m) * invden;
            bf16x8 hv = *(const bf16x8*)(h + (size_t)s * HC + c0);
#pragma unroll
            for (int j = 0; j < 8; j++)
                acc[j] = fmaxf(acc[j], bf2f((unsigned short)hv[j]) * attn);
        }
    }

    bf16x8 ov;
#pragma unroll
    for (int j = 0; j < 8; j++) ov[j] = (short)f2bf(acc[j] + bias[c0 + j]);
    *(bf16x8*)(emb_sel + (size_t)w * HC + c0) = ov;
}

// ---------------------------------------------------------------------------
// bf16 MFMA GEMM:  acc = A @ Wt^T + bias (relu).
// MODE 0: store relu(acc) as bf16 to C.
// MODE 1: fused final layer — p = relu(acc) . W3[0/1], 16-lane shuffle
//         reduce, atomicAdd f32 partials (no C store, h2 never materialized).
// A bf16; Wt fp32 converted in registers during staging. 256x256 tile,
// BK=64, 512 threads (4m x 2n waves). LDS rows padded to 72 shorts.
// ---------------------------------------------------------------------------
#define BK  64
#define LDK 72

__device__ inline bf16x8 cvt8(float4 a, float4 b) {
    bf16x8 r;
    r[0] = (short)f2bf(a.x); r[1] = (short)f2bf(a.y);
    r[2] = (short)f2bf(a.z); r[3] = (short)f2bf(a.w);
    r[4] = (short)f2bf(b.x); r[5] = (short)f2bf(b.y);
    r[6] = (short)f2bf(b.z); r[7] = (short)f2bf(b.w);
    return r;
}

template <int MODE>
__global__ __launch_bounds__(512, 2) void k_gemm(const unsigned short* __restrict__ A, int M,
                                                 const float* __restrict__ Wt,
                                                 const float* __restrict__ bias,
                                                 unsigned short* __restrict__ C,
                                                 const float* __restrict__ W3,
                                                 float* __restrict__ part) {
    __shared__ unsigned short As[256 * LDK];
    __shared__ unsigned short Bs[256 * LDK];
    int tid = threadIdx.x;
    int m0 = blockIdx.y * 256;
    int o0 = blockIdx.x * 256;
    int wv = tid >> 6, lane = tid & 63;
    int wm = wv >> 1, wn = wv & 1;   // 4 x 2 wave grid

    f32x4 acc[4][8];
#pragma unroll
    for (int i = 0; i < 4; i++)
#pragma unroll
        for (int j = 0; j < 8; j++) acc[i][j] = (f32x4){0.f, 0.f, 0.f, 0.f};

    bf16x8 ra[4], rb[4];
#pragma unroll
    for (int s = 0; s < 4; s++) {
        int c = s * 512 + tid;           // 0..2047
        int row = c >> 3, col = (c & 7) * 8;
        int m = m0 + row;
        bf16x8 av = {0, 0, 0, 0, 0, 0, 0, 0};
        if (m < M) av = *(const bf16x8*)(A + (size_t)m * HC + col);
        ra[s] = av;
        const float4* wp = (const float4*)(Wt + (size_t)(o0 + row) * HC + col);
        rb[s] = cvt8(wp[0], wp[1]);
    }

    for (int k0 = 0; k0 < HC; k0 += BK) {
        __syncthreads();
#pragma unroll
        for (int s = 0; s < 4; s++) {
            int c = s * 512 + tid;
            int row = c >> 3, col = (c & 7) * 8;
            *(bf16x8*)(&As[row * LDK + col]) = ra[s];
            *(bf16x8*)(&Bs[row * LDK + col]) = rb[s];
        }
        __syncthreads();

        int kn = k0 + BK;
        if (kn < HC) {
#pragma unroll
            for (int s = 0; s < 4; s++) {
                int c = s * 512 + tid;
                int row = c >> 3, col = (c & 7) * 8;
                int m = m0 + row;
                bf16x8 av = {0, 0, 0, 0, 0, 0, 0, 0};
                if (m < M) av = *(const bf16x8*)(A + (size_t)m * HC + kn + col);
                ra[s] = av;
                const float4* wp = (const float4*)(Wt + (size_t)(o0 + row) * HC + kn + col);
                rb[s] = cvt8(wp[0], wp[1]);
            }
        }

#pragma unroll
        for (int kk = 0; kk < 2; kk++) {
            int kb = kk * 32 + (lane >> 4) * 8;
            bf16x8 af[4], bfr[8];
#pragma unroll
            for (int mi = 0; mi < 4; mi++)
                af[mi] = *(const bf16x8*)(&As[(wm * 64 + mi * 16 + (lane & 15)) * LDK + kb]);
#pragma unroll
            for (int ni = 0; ni < 8; ni++)
                bfr[ni] = *(const bf16x8*)(&Bs[(wn * 128 + ni * 16 + (lane & 15)) * LDK + kb]);
#pragma unroll
            for (int mi = 0; mi < 4; mi++)
#pragma unroll
                for (int ni = 0; ni < 8; ni++)
                    acc[mi][ni] = __builtin_amdgcn_mfma_f32_16x16x32_bf16(
                        af[mi], bfr[ni], acc[mi][ni], 0, 0, 0);
        }
    }

    if (MODE == 0) {
#pragma unroll
        for (int ni = 0; ni < 8; ni++) {
            int ncol = o0 + wn * 128 + ni * 16 + (lane & 15);
            float bv = bias[ncol];
#pragma unroll
            for (int mi = 0; mi < 4; mi++) {
                int mbase = m0 + wm * 64 + mi * 16 + (lane >> 4) * 4;
#pragma unroll
                for (int r = 0; r < 4; r++) {
                    int m = mbase + r;
                    if (m < M) {
                        float v = fmaxf(acc[mi][ni][r] + bv, 0.f);
                        C[(size_t)m * HC + ncol] = f2bf(v);
                    }
                }
            }
        }
    } else {
        // fused final: per-thread dot of relu(acc) fragment with W3 rows
        float p0[4][4], p1[4][4];
#pragma unroll
        for (int mi = 0; mi < 4; mi++)
#pragma unroll
            for (int r = 0; r < 4; r++) { p0[mi][r] = 0.f; p1[mi][r] = 0.f; }
#pragma unroll
        for (int ni = 0; ni < 8; ni++) {
            int ncol = o0 + wn * 128 + ni * 16 + (lane & 15);
            float bv = bias[ncol];
            float w0 = W3[ncol], w1 = W3[HC + ncol];
#pragma unroll
            for (int mi = 0; mi < 4; mi++)
#pragma unroll
                for (int r = 0; r < 4; r++) {
                    float v = fmaxf(acc[mi][ni][r] + bv, 0.f);
                    p0[mi][r] += v * w0;
                    p1[mi][r] += v * w1;
                }
        }
#pragma unroll
        for (int mi = 0; mi < 4; mi++)
#pragma unroll
            for (int r = 0; r < 4; r++) {
                float a0 = p0[mi][r], a1 = p1[mi][r];
#pragma unroll
                for (int off = 8; off >= 1; off >>= 1) {
                    a0 += __shfl_xor(a0, off);
                    a1 += __shfl_xor(a1, off);
                }
                int m = m0 + wm * 64 + mi * 16 + (lane >> 4) * 4 + r;
                if ((lane & 15) == 0 && m < M) {
                    atomicAdd(&part[m * 2 + 0], a0);
                    atomicAdd(&part[m * 2 + 1], a1);
                }
            }
    }
}

// ---------------------------------------------------------------------------
// out[i] = tanh(part[i] + b3[i&1])
// ---------------------------------------------------------------------------
__global__ void k_tanh(const float* __restrict__ part, const float* __restrict__ b3,
                       float* __restrict__ out) {
    int i = blockIdx.x * 256 + threadIdx.x;
    if (i < 2 * M_SEL) out[i] = tanhf(part[i] + b3[i & 1]);
}

// ---------------------------------------------------------------------------
extern "C" void kernel_launch(void* const* d_in, const int* in_sizes, int n_in,
                              void* d_out, int out_size, void* d_ws, size_t ws_size,
                              hipStream_t stream) {
    const float* x       = (const float*)d_in[0];
    const int*   ei      = (const int*)d_in[1];
    const float* W       = (const float*)d_in[3];
    const float* att_src = (const float*)d_in[4];
    const float* att_dst = (const float*)d_in[5];
    const float* bias    = (const float*)d_in[6];
    const float* W1      = (const float*)d_in[7];
    const float* b1      = (const float*)d_in[8];
    const float* W2      = (const float*)d_in[9];
    const float* b2      = (const float*)d_in[10];
    const float* W3      = (const float*)d_in[11];
    const float* b3      = (const float*)d_in[12];
    float* out = (float*)d_out;

    char* ws = (char*)d_ws;
    unsigned short* h       = (unsigned short*)(ws);               // 51,200,000
    unsigned short* emb_sel = (unsigned short*)(ws + 51200000);    // 25,600,000
    unsigned short* h1      = (unsigned short*)(ws + 76800000);    // 25,600,000
    float* part  = (float*)(ws + 102400000);                       //    200,000
    float* a_src = (float*)(ws + 129048576);                       //    800,000
    float* a_dst = (float*)(ws + 129848576);                       //    800,000
    int*   deg   = (int*)  (ws + 130648576);                       //    200,000
    int*   offs  = (int*)  (ws + 130848576);                       //    200,000
    int*   curs  = (int*)  (ws + 131048576);                       //    200,000
    int*   excl  = (int*)  (ws + 131248576);                       //    200,000
    int*   bsum  = (int*)  (ws + 131448576);                       //      1,024
    int*   csr   = (int*)  (ws + 131449600);                       //  1,800,000  (~133 MB)

    hipMemsetAsync(part, 0, 2 * M_SEL * sizeof(float), stream);
    k_transform<<<(N_NODES + 31) / 32, 256, 0, stream>>>(x, W, att_src, att_dst, h,
                                                         a_src, a_dst, deg);
    k_hist<<<(N_EDGES + 255) / 256, 256, 0, stream>>>(ei, deg);
    k_scan1<<<NSCAN_BLK, 256, 0, stream>>>(deg, excl, bsum);
    k_scan3fill<<<NSCAN_BLK, 256, 0, stream>>>(excl, bsum, offs, curs, csr);
    k_fill_edges<<<(N_EDGES + 255) / 256, 256, 0, stream>>>(ei, curs, csr);
    k_aggregate<<<6250, 256, 0, stream>>>(h, a_src, a_dst, csr, offs, deg, bias, emb_sel);

    dim3 g(2, 98);
    k_gemm<0><<<g, 512, 0, stream>>>(emb_sel, M_SEL, W1, b1, h1, nullptr, nullptr);
    k_gemm<1><<<g, 512, 0, stream>>>(h1, M_SEL, W2, b2, nullptr, W3, part);
    k_tanh<<<196, 256, 0, stream>>>(part, b3, out);
}

// Round 8
// 191.054 us; speedup vs baseline: 1.6662x; 1.0036x over previous
//
#include <hip/hip_runtime.h>
#include <hip/hip_bf16.h>
#include <math.h>

#define N_NODES 50000
#define N_EDGES 400000
#define HEADS   4
#define HC      512
#define IN_DIM  5
#define M_SEL   25000
#define NEG_SLOPE 0.2f

typedef __attribute__((ext_vector_type(8))) short bf16x8;
typedef __attribute__((ext_vector_type(4))) float f32x4;

__device__ inline unsigned short f2bf(float f) {
    union { float f; unsigned u; } v; v.f = f;
    unsigned r = v.u + 0x7FFF + ((v.u >> 16) & 1);   // RNE
    return (unsigned short)(r >> 16);
}
__device__ inline float bf2f(unsigned short b) {
    union { unsigned u; float f; } v; v.u = ((unsigned)b) << 16;
    return v.f;
}

// ---------------------------------------------------------------------------
// Kernel 1: h = x @ W.T (bf16); a_src/a_dst einsum [N,4] f32; deg init to 1.
// Register-resident weights (160B contiguous per lane), 8 nodes per wave.
// ---------------------------------------------------------------------------
#define TR_NPW 8

__global__ __launch_bounds__(256) void k_transform(
        const float* __restrict__ x, const float* __restrict__ W,
        const float* __restrict__ att_src, const float* __restrict__ att_dst,
        unsigned short* __restrict__ h, float* __restrict__ a_src,
        float* __restrict__ a_dst, int* __restrict__ deg) {
    int wave = threadIdx.x >> 6, lane = threadIdx.x & 63;
    int c0 = lane * 8;

    float wreg[40];
    const float4* wp = (const float4*)(W + c0 * IN_DIM);
#pragma unroll
    for (int i = 0; i < 10; i++) ((float4*)wreg)[i] = wp[i];
    float sas[8], sad[8];
    *(float4*)&sas[0] = *(const float4*)(att_src + c0);
    *(float4*)&sas[4] = *(const float4*)(att_src + c0 + 4);
    *(float4*)&sad[0] = *(const float4*)(att_dst + c0);
    *(float4*)&sad[4] = *(const float4*)(att_dst + c0 + 4);

    int n0 = (blockIdx.x * 4 + wave) * TR_NPW;
#pragma unroll
    for (int t = 0; t < TR_NPW; t++) {
        int n = n0 + t;
        if (n >= N_NODES) return;
        float xv[IN_DIM];
#pragma unroll
        for (int i = 0; i < IN_DIM; i++) xv[i] = x[n * IN_DIM + i];

        float ps = 0.f, pd = 0.f;
        bf16x8 hv8;
#pragma unroll
        for (int j = 0; j < 8; j++) {
            float acc = 0.f;
#pragma unroll
            for (int i = 0; i < IN_DIM; i++) acc += xv[i] * wreg[j * IN_DIM + i];
            hv8[j] = (short)f2bf(acc);
            ps += acc * sas[j];
            pd += acc * sad[j];
        }
        *(bf16x8*)(h + (size_t)n * HC + c0) = hv8;

#pragma unroll
        for (int off = 8; off >= 1; off >>= 1) {
            ps += __shfl_xor(ps, off);
            pd += __shfl_xor(pd, off);
        }
        if ((lane & 15) == 0) {
            int head = lane >> 4;
            a_src[n * HEADS + head] = ps;
            a_dst[n * HEADS + head] = pd;
        }
        if (lane == 0) deg[n] = 1;   // self-loop base for histogram
    }
}

// ---------------------------------------------------------------------------
// CSR build (multi-block; R4 lesson: never single-block the scan)
// ---------------------------------------------------------------------------
__global__ void k_hist(const int* __restrict__ ei, int* __restrict__ deg) {
    int e = blockIdx.x * 256 + threadIdx.x;
    if (e < N_EDGES) atomicAdd(&deg[ei[N_EDGES + e]], 1);
}

#define NSCAN_BLK 196

__global__ void k_scan1(const int* __restrict__ deg, int* __restrict__ excl,
                        int* __restrict__ bsum) {
    __shared__ int s[256];
    int i = blockIdx.x * 256 + threadIdx.x;
    int v = (i < N_NODES) ? deg[i] : 0;
    s[threadIdx.x] = v;
    __syncthreads();
    for (int off = 1; off < 256; off <<= 1) {
        int t = (threadIdx.x >= off) ? s[threadIdx.x - off] : 0;
        __syncthreads();
        s[threadIdx.x] += t;
        __syncthreads();
    }
    if (i < N_NODES) excl[i] = s[threadIdx.x] - v;
    if (threadIdx.x == 255) bsum[blockIdx.x] = s[255];
}

// each block redundantly scans the 196 block sums (784B, L2-hot), then
// writes offs, self-loop csr slot, and cursor
__global__ void k_scan3fill(const int* __restrict__ excl, const int* __restrict__ bsum,
                            int* __restrict__ offs, int* __restrict__ curs,
                            int* __restrict__ csr) {
    __shared__ int part[256];
    int tid = threadIdx.x;
    part[tid] = (tid < NSCAN_BLK) ? bsum[tid] : 0;
    __syncthreads();
    for (int off = 1; off < 256; off <<= 1) {
        int t = (tid >= off) ? part[tid - off] : 0;
        __syncthreads();
        part[tid] += t;
        __syncthreads();
    }
    int blockoff = (blockIdx.x == 0) ? 0 : part[blockIdx.x - 1];
    int i = blockIdx.x * 256 + tid;
    if (i < N_NODES) {
        int o = excl[i] + blockoff;
        offs[i] = o;
        csr[o] = i;          // self loop in slot 0
        curs[i] = o + 1;
    }
}

__global__ void k_fill_edges(const int* __restrict__ ei, int* __restrict__ cursor,
                             int* __restrict__ csr) {
    int e = blockIdx.x * 256 + threadIdx.x;
    if (e < N_EDGES) {
        int d = ei[N_EDGES + e];
        int pos = atomicAdd(&cursor[d], 1);
        csr[pos] = ei[e];
    }
}

// ---------------------------------------------------------------------------
// Aggregate — TEAM NODES ONLY, one wave per dst node.
// Fast path (dn<=16, ~99.2%): all 16 row gathers are UNCONDITIONAL (csr slot
// clamped to dn-1; dup rows hit L1) so they form one straight-line basic
// block the compiler cannot sink (R6/R7 failure: control-dependent loads
// were moved to their uses, VGPR=44). sched_barrier pins the issue point;
// softmax chain runs under ~16KB of in-flight gather; consume afterwards.
// ---------------------------------------------------------------------------
__global__ __launch_bounds__(256, 4) void k_aggregate(
        const unsigned short* __restrict__ h, const float* __restrict__ a_src,
        const float* __restrict__ a_dst, const int* __restrict__ csr,
        const int* __restrict__ offs, const int* __restrict__ deg,
        const float* __restrict__ bias, unsigned short* __restrict__ emb_sel) {
    int wave = threadIdx.x >> 6, lane = threadIdx.x & 63;
    int w = blockIdx.x * 4 + wave;
    if (w >= M_SEL) return;
    int n = ((w >> 2) << 3) + (w & 3);   // TEAM_IDX[w]

    int base = offs[n];
    int dn = deg[n];
    int head = lane >> 4, egrp = lane & 15;
    int c0 = lane * 8;

    float acc[8];
#pragma unroll
    for (int j = 0; j < 8; j++) acc[j] = -INFINITY;

    if (dn <= 16) {
        // clamped slot: every lane loads a valid csr entry (dn >= 1 always)
        int slot = (egrp < dn) ? egrp : (dn - 1);
        int s_e = csr[base + slot];
        float adn = a_dst[n * HEADS + head];
        float araw = a_src[s_e * HEADS + head];    // valid for all lanes

        // 16 unconditional row gathers — single BB, batched issue
        bf16x8 v[16];
#pragma unroll
        for (int e = 0; e < 16; e++) {
            int s = __shfl(s_e, e);
            v[e] = *(const bf16x8*)(h + (size_t)s * HC + c0);
        }
        __builtin_amdgcn_sched_barrier(0);      // loads stay issued HERE

        // softmax (overlaps gather latency); lanes egrp>=dn masked out
        float t = araw + adn;
        t = (t > 0.f) ? t : NEG_SLOPE * t;
        if (egrp >= dn) t = -INFINITY;
        float m = t;
#pragma unroll
        for (int off = 8; off >= 1; off >>= 1) m = fmaxf(m, __shfl_xor(m, off));
        float ex = (egrp < dn) ? __expf(t - m) : 0.f;
        float den = ex;
#pragma unroll
        for (int off = 8; off >= 1; off >>= 1) den += __shfl_xor(den, off);
        float attn = ex / den;   // this lane's edge attn (for its head)

        // consume (must skip e>=dn: attn=0 would inject 0 into the max)
#pragma unroll
        for (int e = 0; e < 16; e++) {
            if (e < dn) {
                float a = __shfl(attn, (head << 4) | e);
#pragma unroll
                for (int j = 0; j < 8; j++)
                    acc[j] = fmaxf(acc[j], bf2f((unsigned short)v[e][j]) * a);
            }
        }
    } else {
        // fallback: 3-pass (rare, dn>16)
        float adn = a_dst[n * HEADS + head];
        float m = -INFINITY;
        for (int e0 = 0; e0 < dn; e0 += 16) {
            int e = e0 + egrp;
            if (e < dn) {
                int s = csr[base + e];
                float t = a_src[s * HEADS + head] + adn;
                t = (t > 0.f) ? t : NEG_SLOPE * t;
                m = fmaxf(m, t);
            }
        }
#pragma unroll
        for (int off = 8; off >= 1; off >>= 1) m = fmaxf(m, __shfl_xor(m, off));
        float den = 0.f;
        for (int e0 = 0; e0 < dn; e0 += 16) {
            int e = e0 + egrp;
            if (e < dn) {
                int s = csr[base + e];
                float t = a_src[s * HEADS + head] + adn;
                t = (t > 0.f) ? t : NEG_SLOPE * t;
                den += __expf(t - m);
            }
        }
#pragma unroll
        for (int off = 8; off >= 1; off >>= 1) den += __shfl_xor(den, off);
        float invden = 1.0f / den;
        for (int e = 0; e < dn; e++) {
            int s = csr[base + e];
            float t = a_src[s * HEADS + head] + adn;
            t = (t > 0.f) ? t : NEG_SLOPE * t;
            float attn = __expf(t - m) * invden;
            bf16x8 hv = *(const bf16x8*)(h + (size_t)s * HC + c0);
#pragma unroll
            for (int j = 0; j < 8; j++)
                acc[j] = fmaxf(acc[j], bf2f((unsigned short)hv[j]) * attn);
        }
    }

    bf16x8 ov;
#pragma unroll
    for (int j = 0; j < 8; j++) ov[j] = (short)f2bf(acc[j] + bias[c0 + j]);
    *(bf16x8*)(emb_sel + (size_t)w * HC + c0) = ov;
}

// ---------------------------------------------------------------------------
// bf16 MFMA GEMM:  acc = A @ Wt^T + bias (relu).
// MODE 0: store relu(acc) as bf16 to C.
// MODE 1: fused final layer — p = relu(acc) . W3[0/1], 16-lane shuffle
//         reduce, atomicAdd f32 partials (no C store, h2 never materialized).
// A bf16; Wt fp32 converted in registers during staging. 256x256 tile,
// BK=64, 512 threads (4m x 2n waves). LDS rows padded to 72 shorts.
// ---------------------------------------------------------------------------
#define BK  64
#define LDK 72

__device__ inline bf16x8 cvt8(float4 a, float4 b) {
    bf16x8 r;
    r[0] = (short)f2bf(a.x); r[1] = (short)f2bf(a.y);
    r[2] = (short)f2bf(a.z); r[3] = (short)f2bf(a.w);
    r[4] = (short)f2bf(b.x); r[5] = (short)f2bf(b.y);
    r[6] = (short)f2bf(b.z); r[7] = (short)f2bf(b.w);
    return r;
}

template <int MODE>
__global__ __launch_bounds__(512, 2) void k_gemm(const unsigned short* __restrict__ A, int M,
                                                 const float* __restrict__ Wt,
                                                 const float* __restrict__ bias,
                                                 unsigned short* __restrict__ C,
                                                 const float* __restrict__ W3,
                                                 float* __restrict__ part) {
    __shared__ unsigned short As[256 * LDK];
    __shared__ unsigned short Bs[256 * LDK];
    int tid = threadIdx.x;
    int m0 = blockIdx.y * 256;
    int o0 = blockIdx.x * 256;
    int wv = tid >> 6, lane = tid & 63;
    int wm = wv >> 1, wn = wv & 1;   // 4 x 2 wave grid

    f32x4 acc[4][8];
#pragma unroll
    for (int i = 0; i < 4; i++)
#pragma unroll
        for (int j = 0; j < 8; j++) acc[i][j] = (f32x4){0.f, 0.f, 0.f, 0.f};

    bf16x8 ra[4], rb[4];
#pragma unroll
    for (int s = 0; s < 4; s++) {
        int c = s * 512 + tid;           // 0..2047
        int row = c >> 3, col = (c & 7) * 8;
        int m = m0 + row;
        bf16x8 av = {0, 0, 0, 0, 0, 0, 0, 0};
        if (m < M) av = *(const bf16x8*)(A + (size_t)m * HC + col);
        ra[s] = av;
        const float4* wp = (const float4*)(Wt + (size_t)(o0 + row) * HC + col);
        rb[s] = cvt8(wp[0], wp[1]);
    }

    for (int k0 = 0; k0 < HC; k0 += BK) {
        __syncthreads();
#pragma unroll
        for (int s = 0; s < 4; s++) {
            int c = s * 512 + tid;
            int row = c >> 3, col = (c & 7) * 8;
            *(bf16x8*)(&As[row * LDK + col]) = ra[s];
            *(bf16x8*)(&Bs[row * LDK + col]) = rb[s];
        }
        __syncthreads();

        int kn = k0 + BK;
        if (kn < HC) {
#pragma unroll
            for (int s = 0; s < 4; s++) {
                int c = s * 512 + tid;
                int row = c >> 3, col = (c & 7) * 8;
                int m = m0 + row;
                bf16x8 av = {0, 0, 0, 0, 0, 0, 0, 0};
                if (m < M) av = *(const bf16x8*)(A + (size_t)m * HC + kn + col);
                ra[s] = av;
                const float4* wp = (const float4*)(Wt + (size_t)(o0 + row) * HC + kn + col);
                rb[s] = cvt8(wp[0], wp[1]);
            }
        }

#pragma unroll
        for (int kk = 0; kk < 2; kk++) {
            int kb = kk * 32 + (lane >> 4) * 8;
            bf16x8 af[4], bfr[8];
#pragma unroll
            for (int mi = 0; mi < 4; mi++)
                af[mi] = *(const bf16x8*)(&As[(wm * 64 + mi * 16 + (lane & 15)) * LDK + kb]);
#pragma unroll
            for (int ni = 0; ni < 8; ni++)
                bfr[ni] = *(const bf16x8*)(&Bs[(wn * 128 + ni * 16 + (lane & 15)) * LDK + kb]);
#pragma unroll
            for (int mi = 0; mi < 4; mi++)
#pragma unroll
                for (int ni = 0; ni < 8; ni++)
                    acc[mi][ni] = __builtin_amdgcn_mfma_f32_16x16x32_bf16(
                        af[mi], bfr[ni], acc[mi][ni], 0, 0, 0);
        }
    }

    if (MODE == 0) {
#pragma unroll
        for (int ni = 0; ni < 8; ni++) {
            int ncol = o0 + wn * 128 + ni * 16 + (lane & 15);
            float bv = bias[ncol];
#pragma unroll
            for (int mi = 0; mi < 4; mi++) {
                int mbase = m0 + wm * 64 + mi * 16 + (lane >> 4) * 4;
#pragma unroll
                for (int r = 0; r < 4; r++) {
                    int m = mbase + r;
                    if (m < M) {
                        float v = fmaxf(acc[mi][ni][r] + bv, 0.f);
                        C[(size_t)m * HC + ncol] = f2bf(v);
                    }
                }
            }
        }
    } else {
        // fused final: per-thread dot of relu(acc) fragment with W3 rows
        float p0[4][4], p1[4][4];
#pragma unroll
        for (int mi = 0; mi < 4; mi++)
#pragma unroll
            for (int r = 0; r < 4; r++) { p0[mi][r] = 0.f; p1[mi][r] = 0.f; }
#pragma unroll
        for (int ni = 0; ni < 8; ni++) {
            int ncol = o0 + wn * 128 + ni * 16 + (lane & 15);
            float bv = bias[ncol];
            float w0 = W3[ncol], w1 = W3[HC + ncol];
#pragma unroll
            for (int mi = 0; mi < 4; mi++)
#pragma unroll
                for (int r = 0; r < 4; r++) {
                    float v = fmaxf(acc[mi][ni][r] + bv, 0.f);
                    p0[mi][r] += v * w0;
                    p1[mi][r] += v * w1;
                }
        }
#pragma unroll
        for (int mi = 0; mi < 4; mi++)
#pragma unroll
            for (int r = 0; r < 4; r++) {
                float a0 = p0[mi][r], a1 = p1[mi][r];
#pragma unroll
                for (int off = 8; off >= 1; off >>= 1) {
                    a0 += __shfl_xor(a0, off);
                    a1 += __shfl_xor(a1, off);
                }
                int m = m0 + wm * 64 + mi * 16 + (lane >> 4) * 4 + r;
                if ((lane & 15) == 0 && m < M) {
                    atomicAdd(&part[m * 2 + 0], a0);
                    atomicAdd(&part[m * 2 + 1], a1);
                }
            }
    }
}

// ---------------------------------------------------------------------------
// out[i] = tanh(part[i] + b3[i&1])
// ---------------------------------------------------------------------------
__global__ void k_tanh(const float* __restrict__ part, const float* __restrict__ b3,
                       float* __restrict__ out) {
    int i = blockIdx.x * 256 + threadIdx.x;
    if (i < 2 * M_SEL) out[i] = tanhf(part[i] + b3[i & 1]);
}

// ---------------------------------------------------------------------------
extern "C" void kernel_launch(void* const* d_in, const int* in_sizes, int n_in,
                              void* d_out, int out_size, void* d_ws, size_t ws_size,
                              hipStream_t stream) {
    const float* x       = (const float*)d_in[0];
    const int*   ei      = (const int*)d_in[1];
    const float* W       = (const float*)d_in[3];
    const float* att_src = (const float*)d_in[4];
    const float* att_dst = (const float*)d_in[5];
    const float* bias    = (const float*)d_in[6];
    const float* W1      = (const float*)d_in[7];
    const float* b1      = (const float*)d_in[8];
    const float* W2      = (const float*)d_in[9];
    const float* b2      = (const float*)d_in[10];
    const float* W3      = (const float*)d_in[11];
    const float* b3      = (const float*)d_in[12];
    float* out = (float*)d_out;

    char* ws = (char*)d_ws;
    unsigned short* h       = (unsigned short*)(ws);               // 51,200,000
    unsigned short* emb_sel = (unsigned short*)(ws + 51200000);    // 25,600,000
    unsigned short* h1      = (unsigned short*)(ws + 76800000);    // 25,600,000
    float* part  = (float*)(ws + 102400000);                       //    200,000
    float* a_src = (float*)(ws + 129048576);                       //    800,000
    float* a_dst = (float*)(ws + 129848576);                       //    800,000
    int*   deg   = (int*)  (ws + 130648576);                       //    200,000
    int*   offs  = (int*)  (ws + 130848576);                       //    200,000
    int*   curs  = (int*)  (ws + 131048576);                       //    200,000
    int*   excl  = (int*)  (ws + 131248576);                       //    200,000
    int*   bsum  = (int*)  (ws + 131448576);                       //      1,024
    int*   csr   = (int*)  (ws + 131449600);                       //  1,800,000  (~133 MB)

    hipMemsetAsync(part, 0, 2 * M_SEL * sizeof(float), stream);
    k_transform<<<(N_NODES + 31) / 32, 256, 0, stream>>>(x, W, att_src, att_dst, h,
                                                         a_src, a_dst, deg);
    k_hist<<<(N_EDGES + 255) / 256, 256, 0, stream>>>(ei, deg);
    k_scan1<<<NSCAN_BLK, 256, 0, stream>>>(deg, excl, bsum);
    k_scan3fill<<<NSCAN_BLK, 256, 0, stream>>>(excl, bsum, offs, curs, csr);
    k_fill_edges<<<(N_EDGES + 255) / 256, 256, 0, stream>>>(ei, curs, csr);
    k_aggregate<<<6250, 256, 0, stream>>>(h, a_src, a_dst, csr, offs, deg, bias, emb_sel);

    dim3 g(2, 98);
    k_gemm<0><<<g, 512, 0, stream>>>(emb_sel, M_SEL, W1, b1, h1, nullptr, nullptr);
    k_gemm<1><<<g, 512, 0, stream>>>(h1, M_SEL, W2, b2, nullptr, W3, part);
    k_tanh<<<196, 256, 0, stream>>>(part, b3, out);
}

// Round 9
// 190.775 us; speedup vs baseline: 1.6687x; 1.0015x over previous
//
#include <hip/hip_runtime.h>
#include <hip/hip_bf16.h>
#include <math.h>

#define N_NODES 50000
#define N_EDGES 400000
#define HEADS   4
#define HC      512
#define IN_DIM  5
#define M_SEL   25000
#define NEG_SLOPE 0.2f

typedef __attribute__((ext_vector_type(8))) short bf16x8;
typedef __attribute__((ext_vector_type(4))) float f32x4;

__device__ inline unsigned short f2bf(float f) {
    union { float f; unsigned u; } v; v.f = f;
    unsigned r = v.u + 0x7FFF + ((v.u >> 16) & 1);   // RNE
    return (unsigned short)(r >> 16);
}
__device__ inline float bf2f(unsigned short b) {
    union { unsigned u; float f; } v; v.u = ((unsigned)b) << 16;
    return v.f;
}

// ---------------------------------------------------------------------------
// Kernel 1: h = x @ W.T (bf16); a_src/a_dst einsum [N,4] f32; deg init to 1.
// Register-resident weights (160B contiguous per lane), 8 nodes per wave.
// ---------------------------------------------------------------------------
#define TR_NPW 8

__global__ __launch_bounds__(256) void k_transform(
        const float* __restrict__ x, const float* __restrict__ W,
        const float* __restrict__ att_src, const float* __restrict__ att_dst,
        unsigned short* __restrict__ h, float* __restrict__ a_src,
        float* __restrict__ a_dst, int* __restrict__ deg) {
    int wave = threadIdx.x >> 6, lane = threadIdx.x & 63;
    int c0 = lane * 8;

    float wreg[40];
    const float4* wp = (const float4*)(W + c0 * IN_DIM);
#pragma unroll
    for (int i = 0; i < 10; i++) ((float4*)wreg)[i] = wp[i];
    float sas[8], sad[8];
    *(float4*)&sas[0] = *(const float4*)(att_src + c0);
    *(float4*)&sas[4] = *(const float4*)(att_src + c0 + 4);
    *(float4*)&sad[0] = *(const float4*)(att_dst + c0);
    *(float4*)&sad[4] = *(const float4*)(att_dst + c0 + 4);

    int n0 = (blockIdx.x * 4 + wave) * TR_NPW;
#pragma unroll
    for (int t = 0; t < TR_NPW; t++) {
        int n = n0 + t;
        if (n >= N_NODES) return;
        float xv[IN_DIM];
#pragma unroll
        for (int i = 0; i < IN_DIM; i++) xv[i] = x[n * IN_DIM + i];

        float ps = 0.f, pd = 0.f;
        bf16x8 hv8;
#pragma unroll
        for (int j = 0; j < 8; j++) {
            float acc = 0.f;
#pragma unroll
            for (int i = 0; i < IN_DIM; i++) acc += xv[i] * wreg[j * IN_DIM + i];
            hv8[j] = (short)f2bf(acc);
            ps += acc * sas[j];
            pd += acc * sad[j];
        }
        *(bf16x8*)(h + (size_t)n * HC + c0) = hv8;

#pragma unroll
        for (int off = 8; off >= 1; off >>= 1) {
            ps += __shfl_xor(ps, off);
            pd += __shfl_xor(pd, off);
        }
        if ((lane & 15) == 0) {
            int head = lane >> 4;
            a_src[n * HEADS + head] = ps;
            a_dst[n * HEADS + head] = pd;
        }
        if (lane == 0) deg[n] = 1;   // self-loop base for histogram
    }
}

// ---------------------------------------------------------------------------
// CSR build (multi-block; R4 lesson: never single-block the scan)
// ---------------------------------------------------------------------------
__global__ void k_hist(const int* __restrict__ ei, int* __restrict__ deg) {
    int e = blockIdx.x * 256 + threadIdx.x;
    if (e < N_EDGES) atomicAdd(&deg[ei[N_EDGES + e]], 1);
}

#define NSCAN_BLK 196

__global__ void k_scan1(const int* __restrict__ deg, int* __restrict__ excl,
                        int* __restrict__ bsum) {
    __shared__ int s[256];
    int i = blockIdx.x * 256 + threadIdx.x;
    int v = (i < N_NODES) ? deg[i] : 0;
    s[threadIdx.x] = v;
    __syncthreads();
    for (int off = 1; off < 256; off <<= 1) {
        int t = (threadIdx.x >= off) ? s[threadIdx.x - off] : 0;
        __syncthreads();
        s[threadIdx.x] += t;
        __syncthreads();
    }
    if (i < N_NODES) excl[i] = s[threadIdx.x] - v;
    if (threadIdx.x == 255) bsum[blockIdx.x] = s[255];
}

// each block redundantly scans the 196 block sums (784B, L2-hot), then
// writes offs, self-loop csr slot, and cursor
__global__ void k_scan3fill(const int* __restrict__ excl, const int* __restrict__ bsum,
                            int* __restrict__ offs, int* __restrict__ curs,
                            int* __restrict__ csr) {
    __shared__ int part[256];
    int tid = threadIdx.x;
    part[tid] = (tid < NSCAN_BLK) ? bsum[tid] : 0;
    __syncthreads();
    for (int off = 1; off < 256; off <<= 1) {
        int t = (tid >= off) ? part[tid - off] : 0;
        __syncthreads();
        part[tid] += t;
        __syncthreads();
    }
    int blockoff = (blockIdx.x == 0) ? 0 : part[blockIdx.x - 1];
    int i = blockIdx.x * 256 + tid;
    if (i < N_NODES) {
        int o = excl[i] + blockoff;
        offs[i] = o;
        csr[o] = i;          // self loop in slot 0
        curs[i] = o + 1;
    }
}

__global__ void k_fill_edges(const int* __restrict__ ei, int* __restrict__ cursor,
                             int* __restrict__ csr) {
    int e = blockIdx.x * 256 + threadIdx.x;
    if (e < N_EDGES) {
        int d = ei[N_EDGES + e];
        int pos = atomicAdd(&cursor[d], 1);
        csr[pos] = ei[e];
    }
}

// ---------------------------------------------------------------------------
// Aggregate — TEAM NODES ONLY, one wave per dst node.
// Fast path (dn<=16, ~99.2%): FULLY branch-free straight-line block.
//   loads:   all 16 gathers unconditional (slot clamped to dn-1; dups L1-hit)
//   consume: e>=dn uses edge dn-1's attn -> contribution identical to edge
//            dn-1's -> idempotent under fmax (cndmask, no branch).
// With no conditional uses, MachineSink has no target BB (R7/R8 failure mode:
// loads sunk into `if(e<dn)` consumers past sched_barrier); the barrier now
// actually pins 16KB of gather in flight while the softmax chain runs.
// ---------------------------------------------------------------------------
__global__ __launch_bounds__(256, 4) void k_aggregate(
        const unsigned short* __restrict__ h, const float* __restrict__ a_src,
        const float* __restrict__ a_dst, const int* __restrict__ csr,
        const int* __restrict__ offs, const int* __restrict__ deg,
        const float* __restrict__ bias, unsigned short* __restrict__ emb_sel) {
    int wave = threadIdx.x >> 6, lane = threadIdx.x & 63;
    int w = blockIdx.x * 4 + wave;
    if (w >= M_SEL) return;
    int n = ((w >> 2) << 3) + (w & 3);   // TEAM_IDX[w]

    int base = offs[n];
    int dn = deg[n];
    int head = lane >> 4, egrp = lane & 15;
    int c0 = lane * 8;

    float acc[8];
#pragma unroll
    for (int j = 0; j < 8; j++) acc[j] = -INFINITY;

    if (dn <= 16) {
        // clamped slot: every lane loads a valid csr entry (dn >= 1 always)
        int slot = (egrp < dn) ? egrp : (dn - 1);
        int s_e = csr[base + slot];
        float adn = a_dst[n * HEADS + head];
        float araw = a_src[s_e * HEADS + head];

        // 16 unconditional row gathers — batched issue, 16KB in flight
        bf16x8 v[16];
#pragma unroll
        for (int e = 0; e < 16; e++) {
            int s = __shfl(s_e, e);
            v[e] = *(const bf16x8*)(h + (size_t)s * HC + c0);
        }
        __builtin_amdgcn_sched_barrier(0);      // loads stay issued HERE

        // softmax (overlaps gather latency); lanes egrp>=dn masked out
        float t = araw + adn;
        t = (t > 0.f) ? t : NEG_SLOPE * t;
        if (egrp >= dn) t = -INFINITY;
        float m = t;
#pragma unroll
        for (int off = 8; off >= 1; off >>= 1) m = fmaxf(m, __shfl_xor(m, off));
        float ex = (egrp < dn) ? __expf(t - m) : 0.f;
        float den = ex;
#pragma unroll
        for (int off = 8; off >= 1; off >>= 1) den += __shfl_xor(den, off);
        float attn = ex / den;   // this lane's edge attn (for its head)

        // branch-free consume: dup iterations replay edge dn-1 exactly
#pragma unroll
        for (int e = 0; e < 16; e++) {
            int ei = (e < dn) ? e : (dn - 1);          // cndmask, wave-uniform
            float a = __shfl(attn, (head << 4) | ei);
#pragma unroll
            for (int j = 0; j < 8; j++)
                acc[j] = fmaxf(acc[j], bf2f((unsigned short)v[e][j]) * a);
        }
    } else {
        // fallback: 3-pass (rare, dn>16)
        float adn = a_dst[n * HEADS + head];
        float m = -INFINITY;
        for (int e0 = 0; e0 < dn; e0 += 16) {
            int e = e0 + egrp;
            if (e < dn) {
                int s = csr[base + e];
                float t = a_src[s * HEADS + head] + adn;
                t = (t > 0.f) ? t : NEG_SLOPE * t;
                m = fmaxf(m, t);
            }
        }
#pragma unroll
        for (int off = 8; off >= 1; off >>= 1) m = fmaxf(m, __shfl_xor(m, off));
        float den = 0.f;
        for (int e0 = 0; e0 < dn; e0 += 16) {
            int e = e0 + egrp;
            if (e < dn) {
                int s = csr[base + e];
                float t = a_src[s * HEADS + head] + adn;
                t = (t > 0.f) ? t : NEG_SLOPE * t;
                den += __expf(t - m);
            }
        }
#pragma unroll
        for (int off = 8; off >= 1; off >>= 1) den += __shfl_xor(den, off);
        float invden = 1.0f / den;
        for (int e = 0; e < dn; e++) {
            int s = csr[base + e];
            float t = a_src[s * HEADS + head] + adn;
            t = (t > 0.f) ? t : NEG_SLOPE * t;
            float attn = __expf(t - m) * invden;
            bf16x8 hv = *(const bf16x8*)(h + (size_t)s * HC + c0);
#pragma unroll
            for (int j = 0; j < 8; j++)
                acc[j] = fmaxf(acc[j], bf2f((unsigned short)hv[j]) * attn);
        }
    }

    bf16x8 ov;
#pragma unroll
    for (int j = 0; j < 8; j++) ov[j] = (short)f2bf(acc[j] + bias[c0 + j]);
    *(bf16x8*)(emb_sel + (size_t)w * HC + c0) = ov;
}

// ---------------------------------------------------------------------------
// bf16 MFMA GEMM:  acc = A @ Wt^T + bias (relu).
// MODE 0: store relu(acc) as bf16 to C.
// MODE 1: fused final layer — p = relu(acc) . W3[0/1], 16-lane shuffle
//         reduce, atomicAdd f32 partials (no C store, h2 never materialized).
// A bf16; Wt fp32 converted in registers during staging. 256x256 tile,
// BK=64, 512 threads (4m x 2n waves). LDS rows padded to 72 shorts.
// ---------------------------------------------------------------------------
#define BK  64
#define LDK 72

__device__ inline bf16x8 cvt8(float4 a, float4 b) {
    bf16x8 r;
    r[0] = (short)f2bf(a.x); r[1] = (short)f2bf(a.y);
    r[2] = (short)f2bf(a.z); r[3] = (short)f2bf(a.w);
    r[4] = (short)f2bf(b.x); r[5] = (short)f2bf(b.y);
    r[6] = (short)f2bf(b.z); r[7] = (short)f2bf(b.w);
    return r;
}

template <int MODE>
__global__ __launch_bounds__(512, 2) void k_gemm(const unsigned short* __restrict__ A, int M,
                                                 const float* __restrict__ Wt,
                                                 const float* __restrict__ bias,
                                                 unsigned short* __restrict__ C,
                                                 const float* __restrict__ W3,
                                                 float* __restrict__ part) {
    __shared__ unsigned short As[256 * LDK];
    __shared__ unsigned short Bs[256 * LDK];
    int tid = threadIdx.x;
    int m0 = blockIdx.y * 256;
    int o0 = blockIdx.x * 256;
    int wv = tid >> 6, lane = tid & 63;
    int wm = wv >> 1, wn = wv & 1;   // 4 x 2 wave grid

    f32x4 acc[4][8];
#pragma unroll
    for (int i = 0; i < 4; i++)
#pragma unroll
        for (int j = 0; j < 8; j++) acc[i][j] = (f32x4){0.f, 0.f, 0.f, 0.f};

    bf16x8 ra[4], rb[4];
#pragma unroll
    for (int s = 0; s < 4; s++) {
        int c = s * 512 + tid;           // 0..2047
        int row = c >> 3, col = (c & 7) * 8;
        int m = m0 + row;
        bf16x8 av = {0, 0, 0, 0, 0, 0, 0, 0};
        if (m < M) av = *(const bf16x8*)(A + (size_t)m * HC + col);
        ra[s] = av;
        const float4* wp = (const float4*)(Wt + (size_t)(o0 + row) * HC + col);
        rb[s] = cvt8(wp[0], wp[1]);
    }

    for (int k0 = 0; k0 < HC; k0 += BK) {
        __syncthreads();
#pragma unroll
        for (int s = 0; s < 4; s++) {
            int c = s * 512 + tid;
            int row = c >> 3, col = (c & 7) * 8;
            *(bf16x8*)(&As[row * LDK + col]) = ra[s];
            *(bf16x8*)(&Bs[row * LDK + col]) = rb[s];
        }
        __syncthreads();

        int kn = k0 + BK;
        if (kn < HC) {
#pragma unroll
            for (int s = 0; s < 4; s++) {
                int c = s * 512 + tid;
                int row = c >> 3, col = (c & 7) * 8;
                int m = m0 + row;
                bf16x8 av = {0, 0, 0, 0, 0, 0, 0, 0};
                if (m < M) av = *(const bf16x8*)(A + (size_t)m * HC + kn + col);
                ra[s] = av;
                const float4* wp = (const float4*)(Wt + (size_t)(o0 + row) * HC + kn + col);
                rb[s] = cvt8(wp[0], wp[1]);
            }
        }

#pragma unroll
        for (int kk = 0; kk < 2; kk++) {
            int kb = kk * 32 + (lane >> 4) * 8;
            bf16x8 af[4], bfr[8];
#pragma unroll
            for (int mi = 0; mi < 4; mi++)
                af[mi] = *(const bf16x8*)(&As[(wm * 64 + mi * 16 + (lane & 15)) * LDK + kb]);
#pragma unroll
            for (int ni = 0; ni < 8; ni++)
                bfr[ni] = *(const bf16x8*)(&Bs[(wn * 128 + ni * 16 + (lane & 15)) * LDK + kb]);
#pragma unroll
            for (int mi = 0; mi < 4; mi++)
#pragma unroll
                for (int ni = 0; ni < 8; ni++)
                    acc[mi][ni] = __builtin_amdgcn_mfma_f32_16x16x32_bf16(
                        af[mi], bfr[ni], acc[mi][ni], 0, 0, 0);
        }
    }

    if (MODE == 0) {
#pragma unroll
        for (int ni = 0; ni < 8; ni++) {
            int ncol = o0 + wn * 128 + ni * 16 + (lane & 15);
            float bv = bias[ncol];
#pragma unroll
            for (int mi = 0; mi < 4; mi++) {
                int mbase = m0 + wm * 64 + mi * 16 + (lane >> 4) * 4;
#pragma unroll
                for (int r = 0; r < 4; r++) {
                    int m = mbase + r;
                    if (m < M) {
                        float v = fmaxf(acc[mi][ni][r] + bv, 0.f);
                        C[(size_t)m * HC + ncol] = f2bf(v);
                    }
                }
            }
        }
    } else {
        // fused final: per-thread dot of relu(acc) fragment with W3 rows
        float p0[4][4], p1[4][4];
#pragma unroll
        for (int mi = 0; mi < 4; mi++)
#pragma unroll
            for (int r = 0; r < 4; r++) { p0[mi][r] = 0.f; p1[mi][r] = 0.f; }
#pragma unroll
        for (int ni = 0; ni < 8; ni++) {
            int ncol = o0 + wn * 128 + ni * 16 + (lane & 15);
            float bv = bias[ncol];
            float w0 = W3[ncol], w1 = W3[HC + ncol];
#pragma unroll
            for (int mi = 0; mi < 4; mi++)
#pragma unroll
                for (int r = 0; r < 4; r++) {
                    float v = fmaxf(acc[mi][ni][r] + bv, 0.f);
                    p0[mi][r] += v * w0;
                    p1[mi][r] += v * w1;
                }
        }
#pragma unroll
        for (int mi = 0; mi < 4; mi++)
#pragma unroll
            for (int r = 0; r < 4; r++) {
                float a0 = p0[mi][r], a1 = p1[mi][r];
#pragma unroll
                for (int off = 8; off >= 1; off >>= 1) {
                    a0 += __shfl_xor(a0, off);
                    a1 += __shfl_xor(a1, off);
                }
                int m = m0 + wm * 64 + mi * 16 + (lane >> 4) * 4 + r;
                if ((lane & 15) == 0 && m < M) {
                    atomicAdd(&part[m * 2 + 0], a0);
                    atomicAdd(&part[m * 2 + 1], a1);
                }
            }
    }
}

// ---------------------------------------------------------------------------
// out[i] = tanh(part[i] + b3[i&1])
// ---------------------------------------------------------------------------
__global__ void k_tanh(const float* __restrict__ part, const float* __restrict__ b3,
                       float* __restrict__ out) {
    int i = blockIdx.x * 256 + threadIdx.x;
    if (i < 2 * M_SEL) out[i] = tanhf(part[i] + b3[i & 1]);
}

// ---------------------------------------------------------------------------
extern "C" void kernel_launch(void* const* d_in, const int* in_sizes, int n_in,
                              void* d_out, int out_size, void* d_ws, size_t ws_size,
                              hipStream_t stream) {
    const float* x       = (const float*)d_in[0];
    const int*   ei      = (const int*)d_in[1];
    const float* W       = (const float*)d_in[3];
    const float* att_src = (const float*)d_in[4];
    const float* att_dst = (const float*)d_in[5];
    const float* bias    = (const float*)d_in[6];
    const float* W1      = (const float*)d_in[7];
    const float* b1      = (const float*)d_in[8];
    const float* W2      = (const float*)d_in[9];
    const float* b2      = (const float*)d_in[10];
    const float* W3      = (const float*)d_in[11];
    const float* b3      = (const float*)d_in[12];
    float* out = (float*)d_out;

    char* ws = (char*)d_ws;
    unsigned short* h       = (unsigned short*)(ws);               // 51,200,000
    unsigned short* emb_sel = (unsigned short*)(ws + 51200000);    // 25,600,000
    unsigned short* h1      = (unsigned short*)(ws + 76800000);    // 25,600,000
    float* part  = (float*)(ws + 102400000);                       //    200,000
    float* a_src = (float*)(ws + 129048576);                       //    800,000
    float* a_dst = (float*)(ws + 129848576);                       //    800,000
    int*   deg   = (int*)  (ws + 130648576);                       //    200,000
    int*   offs  = (int*)  (ws + 130848576);                       //    200,000
    int*   curs  = (int*)  (ws + 131048576);                       //    200,000
    int*   excl  = (int*)  (ws + 131248576);                       //    200,000
    int*   bsum  = (int*)  (ws + 131448576);                       //      1,024
    int*   csr   = (int*)  (ws + 131449600);                       //  1,800,000  (~133 MB)

    hipMemsetAsync(part, 0, 2 * M_SEL * sizeof(float), stream);
    k_transform<<<(N_NODES + 31) / 32, 256, 0, stream>>>(x, W, att_src, att_dst, h,
                                                         a_src, a_dst, deg);
    k_hist<<<(N_EDGES + 255) / 256, 256, 0, stream>>>(ei, deg);
    k_scan1<<<NSCAN_BLK, 256, 0, stream>>>(deg, excl, bsum);
    k_scan3fill<<<NSCAN_BLK, 256, 0, stream>>>(excl, bsum, offs, curs, csr);
    k_fill_edges<<<(N_EDGES + 255) / 256, 256, 0, stream>>>(ei, curs, csr);
    k_aggregate<<<6250, 256, 0, stream>>>(h, a_src, a_dst, csr, offs, deg, bias, emb_sel);

    dim3 g(2, 98);
    k_gemm<0><<<g, 512, 0, stream>>>(emb_sel, M_SEL, W1, b1, h1, nullptr, nullptr);
    k_gemm<1><<<g, 512, 0, stream>>>(h1, M_SEL, W2, b2, nullptr, W3, part);
    k_tanh<<<196, 256, 0, stream>>>(part, b3, out);
}